// Round 1
// baseline (1256.949 us; speedup 1.0000x reference)
//
#include <hip/hip_runtime.h>

// ============================================================================
// GAT classifier, N=8192, DIN=768.
// Key identity: softmax over e_ij = s_i + d_j cancels s_i:
//   Z = (A @ (u*H)) / (A @ u),  u = exp(H @ a_dst).
// So each GAT layer is: small GEMM -> masked-sum over neighbors -> row epilogue.
// A (int32, 268MB) is read from HBM exactly once (fused bitpack in k_attn1);
// layer 2 reads the 8MB bitmask.
// ============================================================================

#define NN 8192

// ---- workspace layout (bytes) ----
// [0,       8MB)  : Wbits  u32[8192*256] neighbor bitmask
// [8MB,    10MB)  : G1     f32[8192*64]  = u1 * H1
// [10MB+0k ) u1[8192], +32k den1[8192], +64k u2[8192], +96k den2[8192]
// [10MB+128k, +1MB): G2    f32[8192*32]
// [11MB+128k, +256k): gpart f32[1024*64]
// [12MB,   28MB)  : nump   (num1p[8][8192][64], later aliased by num2p[16][8192][32])
static constexpr size_t OFF_WBITS = 0;
static constexpr size_t OFF_G1    = (size_t)8  << 20;
static constexpr size_t OFF_U1    = (size_t)10 << 20;
static constexpr size_t OFF_DEN1  = ((size_t)10 << 20) + 32 * 1024;
static constexpr size_t OFF_U2    = ((size_t)10 << 20) + 64 * 1024;
static constexpr size_t OFF_DEN2  = ((size_t)10 << 20) + 96 * 1024;
static constexpr size_t OFF_G2    = ((size_t)10 << 20) + 128 * 1024;
static constexpr size_t OFF_GPART = ((size_t)10 << 20) + 128 * 1024 + ((size_t)1 << 20);
static constexpr size_t OFF_NUMP  = (size_t)12 << 20;

__device__ __forceinline__ float elu_f(float x) {
    return x > 0.f ? x : expm1f(x);   // jax.nn.elu uses expm1
}

// ---------------------------------------------------------------------------
// K2: H1 = X @ W1 ; d1 = H1 @ a1[64:128]; u1 = exp(d1); G1 = u1 * H1.
// 32 rows/block, thread = (row, 8-col group). X tile in LDS, W1 from global
// (196KB, L1/L2-resident broadcast).
// ---------------------------------------------------------------------------
__global__ __launch_bounds__(256) void k_xw1(const float* __restrict__ X,
                                             const float* __restrict__ W1,
                                             const float* __restrict__ a1,
                                             float* __restrict__ G1,
                                             float* __restrict__ u1) {
    __shared__ float Xt[32][65];     // +1 pad: conflict-free column reads
    __shared__ float red[32][8];
    __shared__ float us[32];
    const int tid = threadIdx.x;
    const int row = tid & 31, cg = tid >> 5;   // 8 col-groups * 8 cols
    const int row0 = blockIdx.x * 32;
    float acc[8];
#pragma unroll
    for (int i = 0; i < 8; ++i) acc[i] = 0.f;
    const float4* X4 = (const float4*)X;
    for (int k0 = 0; k0 < 768; k0 += 64) {
        __syncthreads();
#pragma unroll
        for (int f = tid; f < 512; f += 256) {
            int r = f >> 4, q = f & 15;
            float4 v = X4[(size_t)(row0 + r) * 192 + (k0 >> 2) + q];
            Xt[r][q * 4 + 0] = v.x; Xt[r][q * 4 + 1] = v.y;
            Xt[r][q * 4 + 2] = v.z; Xt[r][q * 4 + 3] = v.w;
        }
        __syncthreads();
        const float4* W4 = (const float4*)(W1 + (size_t)k0 * 64);
        for (int kk = 0; kk < 64; ++kk) {
            float x = Xt[row][kk];
            float4 w0 = W4[kk * 16 + cg * 2];
            float4 w1 = W4[kk * 16 + cg * 2 + 1];
            acc[0] += x * w0.x; acc[1] += x * w0.y;
            acc[2] += x * w0.z; acc[3] += x * w0.w;
            acc[4] += x * w1.x; acc[5] += x * w1.y;
            acc[6] += x * w1.z; acc[7] += x * w1.w;
        }
    }
    // d1 partial over this thread's 8 cols
    float p = 0.f;
#pragma unroll
    for (int i = 0; i < 8; ++i) p += acc[i] * a1[64 + cg * 8 + i];
    red[row][cg] = p;
    __syncthreads();
    if (tid < 32) {
        float d = 0.f;
#pragma unroll
        for (int g = 0; g < 8; ++g) d += red[tid][g];
        float uv = expf(d);
        u1[row0 + tid] = uv;
        us[tid] = uv;
    }
    __syncthreads();
    float uv = us[row];
    float4 o0 = make_float4(acc[0] * uv, acc[1] * uv, acc[2] * uv, acc[3] * uv);
    float4 o1 = make_float4(acc[4] * uv, acc[5] * uv, acc[6] * uv, acc[7] * uv);
    float4* G4o = (float4*)(G1 + (size_t)(row0 + row) * 64 + cg * 8);
    G4o[0] = o0; G4o[1] = o1;
}

// ---------------------------------------------------------------------------
// K3: layer-1 masked accumulate, fused with bit-packing of A.
// grid (64 rowtiles, 8 k-splits); block = 256.
// Phase 1: stream A rows (HBM, once globally), __ballot-pack to LDS + Wbits.
// Phase 2: num1p[s][row][c] = sum_j bit(row,j) * G1[j][c]; 2 rows x 16 cols/thread.
// G1 rows read via float4 from global (2MB, L1/L2-hot).
// ---------------------------------------------------------------------------
__global__ __launch_bounds__(256) void k_attn1(const int* __restrict__ A,
                                               const float* __restrict__ G1,
                                               unsigned long long* __restrict__ Wb64,
                                               float* __restrict__ num1p) {
    __shared__ unsigned int bw[128][32];   // 128 rows x 1024 j-bits = 16KB
    const int tid = threadIdx.x;
    const int wv = tid >> 6, lane = tid & 63;
    const int row0 = blockIdx.x * 128;
    const int jbase = blockIdx.y * 1024;

    // ---- pack: 128 rows x 16 chunks of 64; 512 chunks/wave, batched 16 ----
    for (int base = wv * 512; base < wv * 512 + 512; base += 16) {
        int v[16];
#pragma unroll
        for (int t = 0; t < 16; ++t) {
            int cid = base + t;
            int r = cid >> 4, h = cid & 15;
            v[t] = A[(size_t)(row0 + r) * NN + jbase + h * 64 + lane];
        }
#pragma unroll
        for (int t = 0; t < 16; ++t) {
            int cid = base + t;
            int r = cid >> 4, h = cid & 15;
            unsigned long long m = __ballot(v[t] != 0);
            if (lane == 0) {
                *(unsigned long long*)&bw[r][h * 2] = m;
                Wb64[(size_t)(row0 + r) * 128 + (jbase >> 6) + h] = m;
            }
        }
    }
    __syncthreads();

    // ---- masked accumulate ----
    const int cg = tid & 3;          // 4 col-groups x 16 cols = 64
    const int tr = tid >> 2;         // rows tr, tr+64
    float acc0[16], acc1[16];
#pragma unroll
    for (int i = 0; i < 16; ++i) { acc0[i] = 0.f; acc1[i] = 0.f; }
    const float4* G4 = (const float4*)G1;
    for (int jw = 0; jw < 32; ++jw) {
        unsigned int w0 = bw[tr][jw];
        unsigned int w1 = bw[tr + 64][jw];
#pragma unroll 8
        for (int b = 0; b < 32; ++b) {
            int j = jbase + jw * 32 + b;
            float f0 = (float)((w0 >> b) & 1u);
            float f1 = (float)((w1 >> b) & 1u);
#pragma unroll
            for (int q = 0; q < 4; ++q) {
                float4 g = G4[(size_t)j * 16 + cg * 4 + q];
                acc0[q * 4 + 0] += f0 * g.x; acc0[q * 4 + 1] += f0 * g.y;
                acc0[q * 4 + 2] += f0 * g.z; acc0[q * 4 + 3] += f0 * g.w;
                acc1[q * 4 + 0] += f1 * g.x; acc1[q * 4 + 1] += f1 * g.y;
                acc1[q * 4 + 2] += f1 * g.z; acc1[q * 4 + 3] += f1 * g.w;
            }
        }
    }
    const int s = blockIdx.y;
    float4* O4 = (float4*)num1p;
    size_t b0 = ((size_t)s * NN + row0 + tr) * 16 + cg * 4;
    size_t b1 = ((size_t)s * NN + row0 + tr + 64) * 16 + cg * 4;
#pragma unroll
    for (int q = 0; q < 4; ++q) {
        O4[b0 + q] = make_float4(acc0[q*4+0], acc0[q*4+1], acc0[q*4+2], acc0[q*4+3]);
        O4[b1 + q] = make_float4(acc1[q*4+0], acc1[q*4+1], acc1[q*4+2], acc1[q*4+3]);
    }
}

// ---------------------------------------------------------------------------
// den[i] = sum_j bit(i,j) * u[j].  One wave per row; bits via uniform u64 load
// (scalarized), u coalesced; 64-lane shuffle reduce.
// ---------------------------------------------------------------------------
__global__ __launch_bounds__(256) void k_den(const unsigned long long* __restrict__ Wb64,
                                             const float* __restrict__ u,
                                             float* __restrict__ den) {
    const int tid = threadIdx.x, wv = tid >> 6, lane = tid & 63;
    const int row = blockIdx.x * 4 + wv;
    float s = 0.f;
    for (int w = 0; w < 128; ++w) {
        unsigned long long bits = Wb64[(size_t)row * 128 + w];
        float uv = u[w * 64 + lane];
        s += ((bits >> lane) & 1ull) ? uv : 0.f;
    }
#pragma unroll
    for (int off = 32; off; off >>= 1) s += __shfl_down(s, off);
    if (lane == 0) den[row] = s;
}

// ---------------------------------------------------------------------------
// K4: per-row epilogue of layer 1 + layer-2 prep. One wave per row.
// Z1 = (sum_s num1p)/den1 ; out1 = elu(Z1@W21+b21); H2 = out1@Wg2;
// d2 = H2 . a2[32:]; u2 = exp(d2); G2 = u2*H2.
// ---------------------------------------------------------------------------
__global__ __launch_bounds__(256) void k_ep1(const float* __restrict__ num1p,
                                             const float* __restrict__ den1,
                                             const float* __restrict__ W21,
                                             const float* __restrict__ b21,
                                             const float* __restrict__ Wg2,
                                             const float* __restrict__ a2,
                                             float* __restrict__ G2,
                                             float* __restrict__ u2) {
    __shared__ float zsh[4][64];
    __shared__ float osh[4][64];
    const int tid = threadIdx.x, wv = tid >> 6, lane = tid & 63;
    const int row = blockIdx.x * 4 + wv;
    float s = 0.f;
#pragma unroll
    for (int sp = 0; sp < 8; ++sp)
        s += num1p[((size_t)sp * NN + row) * 64 + lane];
    float z = s / den1[row];
    zsh[wv][lane] = z;
    __syncthreads();
    float o = b21[lane];
    for (int c = 0; c < 64; ++c) o += zsh[wv][c] * W21[c * 64 + lane];
    o = elu_f(o);
    osh[wv][lane] = o;
    __syncthreads();
    const int l32 = lane & 31;
    float h = 0.f;
    for (int c = 0; c < 64; ++c) h += osh[wv][c] * Wg2[c * 32 + l32];
    float p = (lane < 32) ? h * a2[32 + l32] : 0.f;
#pragma unroll
    for (int off = 32; off; off >>= 1) p += __shfl_down(p, off);
    float d2 = __shfl(p, 0);
    float uu = expf(d2);
    if (lane < 32) G2[(size_t)row * 32 + lane] = uu * h;
    if (lane == 0) u2[row] = uu;
}

// ---------------------------------------------------------------------------
// K5: layer-2 masked accumulate. grid (32 rowtiles, 16 k-splits).
// Bits staged from Wbits (8MB, L2/L3); G2 rows via float4 from global.
// 2 rows x 16 cols per thread (C=32 total).
// ---------------------------------------------------------------------------
__global__ __launch_bounds__(256) void k_attn2(const unsigned int* __restrict__ Wbits,
                                               const float* __restrict__ G2,
                                               float* __restrict__ num2p) {
    __shared__ unsigned int bw[256][16];   // 256 rows x 512 j-bits = 16KB
    const int tid = threadIdx.x;
    const int row0 = blockIdx.x * 256;
    const int jbase = blockIdx.y * 512;
    {
        const uint4* Wb4 = (const uint4*)(Wbits + (size_t)(row0 + tid) * 256 + (jbase >> 5));
#pragma unroll
        for (int q = 0; q < 4; ++q) {
            uint4 v = Wb4[q];
            bw[tid][q * 4 + 0] = v.x; bw[tid][q * 4 + 1] = v.y;
            bw[tid][q * 4 + 2] = v.z; bw[tid][q * 4 + 3] = v.w;
        }
    }
    __syncthreads();
    const int cg = tid & 1;          // 2 col-groups x 16 = 32 cols
    const int tr = tid >> 1;         // rows tr, tr+128
    float acc0[16], acc1[16];
#pragma unroll
    for (int i = 0; i < 16; ++i) { acc0[i] = 0.f; acc1[i] = 0.f; }
    const float4* G4 = (const float4*)G2;
    for (int jw = 0; jw < 16; ++jw) {
        unsigned int w0 = bw[tr][jw];
        unsigned int w1 = bw[tr + 128][jw];
#pragma unroll 8
        for (int b = 0; b < 32; ++b) {
            int j = jbase + jw * 32 + b;
            float f0 = (float)((w0 >> b) & 1u);
            float f1 = (float)((w1 >> b) & 1u);
#pragma unroll
            for (int q = 0; q < 4; ++q) {
                float4 g = G4[(size_t)j * 8 + cg * 4 + q];
                acc0[q * 4 + 0] += f0 * g.x; acc0[q * 4 + 1] += f0 * g.y;
                acc0[q * 4 + 2] += f0 * g.z; acc0[q * 4 + 3] += f0 * g.w;
                acc1[q * 4 + 0] += f1 * g.x; acc1[q * 4 + 1] += f1 * g.y;
                acc1[q * 4 + 2] += f1 * g.z; acc1[q * 4 + 3] += f1 * g.w;
            }
        }
    }
    const int s = blockIdx.y;
    float4* O4 = (float4*)num2p;
    size_t b0 = ((size_t)s * NN + row0 + tr) * 8 + cg * 4;
    size_t b1 = ((size_t)s * NN + row0 + tr + 128) * 8 + cg * 4;
#pragma unroll
    for (int q = 0; q < 4; ++q) {
        O4[b0 + q] = make_float4(acc0[q*4+0], acc0[q*4+1], acc0[q*4+2], acc0[q*4+3]);
        O4[b1 + q] = make_float4(acc1[q*4+0], acc1[q*4+1], acc1[q*4+2], acc1[q*4+3]);
    }
}

// ---------------------------------------------------------------------------
// K6: layer-2 epilogue + columnwise partial sums for the mean.
// One wave per 2 rows; block partial -> gpart[block][64].
// ---------------------------------------------------------------------------
__global__ __launch_bounds__(256) void k_ep2(const float* __restrict__ num2p,
                                             const float* __restrict__ den2,
                                             const float* __restrict__ W22,
                                             const float* __restrict__ b22,
                                             float* __restrict__ gpart) {
    __shared__ float zsh[4][32];
    __shared__ float gsh[4][64];
    const int tid = threadIdx.x, wv = tid >> 6, lane = tid & 63;
    float greg = 0.f;
    for (int it = 0; it < 2; ++it) {
        const int row = blockIdx.x * 8 + wv * 2 + it;
        if (lane < 32) {
            float s = 0.f;
#pragma unroll
            for (int sp = 0; sp < 16; ++sp)
                s += num2p[((size_t)sp * NN + row) * 32 + lane];
            zsh[wv][lane] = s / den2[row];
        }
        __syncthreads();
        float o = b22[lane];
        for (int c = 0; c < 32; ++c) o += zsh[wv][c] * W22[c * 64 + lane];
        greg += elu_f(o);
        __syncthreads();
    }
    gsh[wv][lane] = greg;
    __syncthreads();
    if (tid < 64)
        gpart[(size_t)blockIdx.x * 64 + tid] =
            gsh[0][tid] + gsh[1][tid] + gsh[2][tid] + gsh[3][tid];
}

// ---------------------------------------------------------------------------
// K7: reduce gpart -> g (mean), then MLP head -> d_out[2].
// ---------------------------------------------------------------------------
__global__ __launch_bounds__(64) void k_head(const float* __restrict__ gpart,
                                             const float* __restrict__ M1,
                                             const float* __restrict__ bm1,
                                             const float* __restrict__ M2,
                                             const float* __restrict__ bm2,
                                             float* __restrict__ outp) {
    __shared__ float gsh[64];
    __shared__ float hsh[64];
    const int tid = threadIdx.x;
    float s = 0.f;
    for (int b = 0; b < 1024; ++b) s += gpart[b * 64 + tid];
    gsh[tid] = s * (1.0f / 8192.0f);
    __syncthreads();
    float h = bm1[tid];
    for (int c = 0; c < 64; ++c) h += gsh[c] * M1[c * 64 + tid];
    hsh[tid] = h > 0.f ? h : 0.f;
    __syncthreads();
    if (tid < 2) {
        float o = bm2[tid];
        for (int j = 0; j < 64; ++j) o += hsh[j] * M2[j * 2 + tid];
        outp[tid] = o;
    }
}

// ---------------------------------------------------------------------------
extern "C" void kernel_launch(void* const* d_in, const int* in_sizes, int n_in,
                              void* d_out, int out_size, void* d_ws, size_t ws_size,
                              hipStream_t stream) {
    const float* X   = (const float*)d_in[0];
    const int*   A   = (const int*)  d_in[1];
    const float* W1  = (const float*)d_in[2];
    const float* a1  = (const float*)d_in[3];
    const float* W21 = (const float*)d_in[4];
    const float* b21 = (const float*)d_in[5];
    const float* Wg2 = (const float*)d_in[6];
    const float* a2  = (const float*)d_in[7];
    const float* W22 = (const float*)d_in[8];
    const float* b22 = (const float*)d_in[9];
    const float* M1  = (const float*)d_in[10];
    const float* bm1 = (const float*)d_in[11];
    const float* M2  = (const float*)d_in[12];
    const float* bm2 = (const float*)d_in[13];
    float* out = (float*)d_out;

    char* ws = (char*)d_ws;
    unsigned int*       Wbits = (unsigned int*)(ws + OFF_WBITS);
    unsigned long long* Wb64  = (unsigned long long*)(ws + OFF_WBITS);
    float* G1    = (float*)(ws + OFF_G1);
    float* u1    = (float*)(ws + OFF_U1);
    float* den1  = (float*)(ws + OFF_DEN1);
    float* u2    = (float*)(ws + OFF_U2);
    float* den2  = (float*)(ws + OFF_DEN2);
    float* G2    = (float*)(ws + OFF_G2);
    float* gpart = (float*)(ws + OFF_GPART);
    float* nump  = (float*)(ws + OFF_NUMP);   // num1p, later reused as num2p

    k_xw1 <<<256, 256, 0, stream>>>(X, W1, a1, G1, u1);
    k_attn1<<<dim3(64, 8), 256, 0, stream>>>(A, G1, Wb64, nump);
    k_den  <<<2048, 256, 0, stream>>>(Wb64, u1, den1);
    k_ep1  <<<2048, 256, 0, stream>>>(nump, den1, W21, b21, Wg2, a2, G2, u2);
    k_den  <<<2048, 256, 0, stream>>>(Wb64, u2, den2);
    k_attn2<<<dim3(32, 16), 256, 0, stream>>>(Wbits, G2, nump);
    k_ep2  <<<1024, 256, 0, stream>>>(nump, den2, W22, b22, gpart);
    k_head <<<1, 64, 0, stream>>>(gpart, M1, bm1, M2, bm2, out);
}

// Round 2
// 785.672 us; speedup vs baseline: 1.5998x; 1.5998x over previous
//
#include <hip/hip_runtime.h>

// ============================================================================
// GAT classifier, N=8192. Softmax cancels the source term:
//   Z = (A @ (u*H)) / (A @ u),  u = exp(H @ a_dst).
// Round 2: masked-sum num = A@G computed on MFMA as num^T = G^T · A^T with
// bf16 hi/lo split (G = Ghi + Glo, A exact in bf16). Adjacency bits expand to
// bf16 {0,1} fragments via a 256-entry LDS LUT (1 ds_read_b128 per fragment).
// A (268MB) is read from HBM exactly once (pack fused into k_attn1).
// ============================================================================

#define NN 8192

typedef __attribute__((ext_vector_type(8))) short s16x8;   // 8 bf16 (4 VGPR)
typedef __attribute__((ext_vector_type(4))) float f32x4;   // MFMA C/D
union V16 { uint4 u; s16x8 s; };

// ---- workspace layout ----
static constexpr size_t OFF_WBITS = 0;                               // 8 MB bitmask
static constexpr size_t OFF_GT1H  = (size_t)8 << 20;                 // 1 MB  G1^T hi bf16 [64][8192]
static constexpr size_t OFF_GT1L  = (size_t)9 << 20;                 // 1 MB  G1^T lo
static constexpr size_t OFF_U1    = (size_t)10 << 20;
static constexpr size_t OFF_DEN1  = ((size_t)10 << 20) + 32 * 1024;
static constexpr size_t OFF_U2    = ((size_t)10 << 20) + 64 * 1024;
static constexpr size_t OFF_DEN2  = ((size_t)10 << 20) + 96 * 1024;
static constexpr size_t OFF_GT2H  = ((size_t)10 << 20) + 128 * 1024; // 512 KB G2^T hi [32][8192]
static constexpr size_t OFF_GT2L  = ((size_t)10 << 20) + 640 * 1024; // 512 KB G2^T lo
static constexpr size_t OFF_GPART = ((size_t)11 << 20) + 256 * 1024; // 256 KB
static constexpr size_t OFF_NUMP  = (size_t)12 << 20;                // 16 MB partials

__device__ __forceinline__ float elu_f(float x) {
    return x > 0.f ? x : expm1f(x);
}
__device__ __forceinline__ unsigned int bf16_rne(float x) {
    unsigned int u = __float_as_uint(x);
    return (u + 0x7FFFu + ((u >> 16) & 1u)) >> 16;
}
// pack (hi<<16)|lo where G ~= bf16(hi) + bf16(lo)
__device__ __forceinline__ unsigned int split_pack(float g) {
    unsigned int hi = bf16_rne(g);
    float fhi = __uint_as_float(hi << 16);
    unsigned int lo = bf16_rne(g - fhi);
    return (hi << 16) | lo;
}

// ---------------------------------------------------------------------------
// K1: H1 = X @ W1 ; u1 = exp(H1 @ a1[64:]); G1 = u1*H1 -> transposed bf16
// hi/lo [feat][node] for the MFMA A-operand.
// ---------------------------------------------------------------------------
__global__ __launch_bounds__(256) void k_xw1(const float* __restrict__ X,
                                             const float* __restrict__ W1,
                                             const float* __restrict__ a1,
                                             unsigned int* __restrict__ Gt1h,
                                             unsigned int* __restrict__ Gt1l,
                                             float* __restrict__ u1) {
    __shared__ float Xt[32][65];
    __shared__ float red[32][8];
    __shared__ float us[32];
    __shared__ unsigned int Gsh[64][33];   // packed hi|lo, [feat][node]
    const int tid = threadIdx.x;
    const int row = tid & 31, cg = tid >> 5;
    const int row0 = blockIdx.x * 32;
    float acc[8];
#pragma unroll
    for (int i = 0; i < 8; ++i) acc[i] = 0.f;
    const float4* X4 = (const float4*)X;
    for (int k0 = 0; k0 < 768; k0 += 64) {
        __syncthreads();
#pragma unroll
        for (int f = tid; f < 512; f += 256) {
            int r = f >> 4, q = f & 15;
            float4 v = X4[(size_t)(row0 + r) * 192 + (k0 >> 2) + q];
            Xt[r][q * 4 + 0] = v.x; Xt[r][q * 4 + 1] = v.y;
            Xt[r][q * 4 + 2] = v.z; Xt[r][q * 4 + 3] = v.w;
        }
        __syncthreads();
        const float4* W4 = (const float4*)(W1 + (size_t)k0 * 64);
        for (int kk = 0; kk < 64; ++kk) {
            float x = Xt[row][kk];
            float4 w0 = W4[kk * 16 + cg * 2];
            float4 w1 = W4[kk * 16 + cg * 2 + 1];
            acc[0] += x * w0.x; acc[1] += x * w0.y;
            acc[2] += x * w0.z; acc[3] += x * w0.w;
            acc[4] += x * w1.x; acc[5] += x * w1.y;
            acc[6] += x * w1.z; acc[7] += x * w1.w;
        }
    }
    float p = 0.f;
#pragma unroll
    for (int i = 0; i < 8; ++i) p += acc[i] * a1[64 + cg * 8 + i];
    red[row][cg] = p;
    __syncthreads();
    if (tid < 32) {
        float d = 0.f;
#pragma unroll
        for (int g = 0; g < 8; ++g) d += red[tid][g];
        float uv = expf(d);
        u1[row0 + tid] = uv;
        us[tid] = uv;
    }
    __syncthreads();
    float uv = us[row];
#pragma unroll
    for (int i = 0; i < 8; ++i)
        Gsh[cg * 8 + i][row] = split_pack(acc[i] * uv);
    __syncthreads();
    if (tid < 64) {   // feat = tid; write 32-node runs of hi and lo rows
        unsigned int v[32];
#pragma unroll
        for (int j = 0; j < 32; ++j) v[j] = Gsh[tid][j];
        unsigned int base = tid * 4096 + blockIdx.x * 16;
        uint4* H4 = (uint4*)(Gt1h + base);
        uint4* L4 = (uint4*)(Gt1l + base);
#pragma unroll
        for (int i = 0; i < 4; ++i) {
            uint4 hp, lp;
            hp.x = (v[i*8+0] >> 16) | (v[i*8+1] & 0xFFFF0000u);
            hp.y = (v[i*8+2] >> 16) | (v[i*8+3] & 0xFFFF0000u);
            hp.z = (v[i*8+4] >> 16) | (v[i*8+5] & 0xFFFF0000u);
            hp.w = (v[i*8+6] >> 16) | (v[i*8+7] & 0xFFFF0000u);
            lp.x = (v[i*8+0] & 0xFFFFu) | (v[i*8+1] << 16);
            lp.y = (v[i*8+2] & 0xFFFFu) | (v[i*8+3] << 16);
            lp.z = (v[i*8+4] & 0xFFFFu) | (v[i*8+5] << 16);
            lp.w = (v[i*8+6] & 0xFFFFu) | (v[i*8+7] << 16);
            H4[i] = hp; L4[i] = lp;
        }
    }
}

// ---------------------------------------------------------------------------
// LUT: byte -> 8 packed bf16 {0,1}. Built per block (4KB LDS).
// ---------------------------------------------------------------------------
__device__ __forceinline__ void build_lut(uint4* lut, int tid) {
    unsigned int b = (unsigned int)tid;
    uint4 e;
    e.x = ((b & 1u)   ? 0x3F80u : 0u) | ((b & 2u)   ? 0x3F800000u : 0u);
    e.y = ((b & 4u)   ? 0x3F80u : 0u) | ((b & 8u)   ? 0x3F800000u : 0u);
    e.z = ((b & 16u)  ? 0x3F80u : 0u) | ((b & 32u)  ? 0x3F800000u : 0u);
    e.w = ((b & 64u)  ? 0x3F80u : 0u) | ((b & 128u) ? 0x3F800000u : 0u);
    lut[tid] = e;
}

// ---------------------------------------------------------------------------
// K2: fused pack + layer-1 MFMA. grid (128 node-groups of 64, 8 k-chunks of
// 1024). Pack: stream A (HBM once), ballot -> LDS (padded) + global Wb64.
// MFMA: num1^T tile = Gt1^T(hi,lo) x bits; wave wv = n-tile wv, 4 m-tiles.
// ---------------------------------------------------------------------------
__global__ __launch_bounds__(256) void k_attn1(const int* __restrict__ A,
                                               const unsigned int* __restrict__ Gt1h,
                                               const unsigned int* __restrict__ Gt1l,
                                               unsigned long long* __restrict__ Wb64,
                                               float* __restrict__ num1p) {
    __shared__ uint4 lut[256];
    __shared__ unsigned long long bwp[64 * 17];   // 64 rows x 16 u64, +1 pad
    const int tid = threadIdx.x, wv = tid >> 6, lane = tid & 63;
    const int node0 = blockIdx.x * 64;
    const int kbase = blockIdx.y * 1024;
    build_lut(lut, tid);

    // ---- pack: wave wv handles rows wv*16..+15, 16 u64-words each ----
    for (int base = wv * 256; base < wv * 256 + 256; base += 8) {
        int v[8];
#pragma unroll
        for (int t = 0; t < 8; ++t) {
            int c = base + t, r = c >> 4, h = c & 15;
            v[t] = A[(size_t)(node0 + r) * NN + kbase + h * 64 + lane];
        }
#pragma unroll
        for (int t = 0; t < 8; ++t) {
            int c = base + t, r = c >> 4, h = c & 15;
            unsigned long long m = __ballot(v[t] != 0);
            if (lane == 0) {
                Wb64[(size_t)(node0 + r) * 128 + (kbase >> 6) + h] = m;
                bwp[r * 17 + h] = m;
            }
        }
    }
    __syncthreads();

    // ---- MFMA ----
    const int n = lane & 15, quad = lane >> 4;
    const int nt = wv;
    const unsigned int* bw32 = (const unsigned int*)bwp;
    const int brow = (nt * 16 + n) * 34;
    size_t goff[4];
#pragma unroll
    for (int mt = 0; mt < 4; ++mt)
        goff[mt] = (size_t)(mt * 16 + n) * 4096 + (kbase >> 1) + quad * 4;
    f32x4 acc[4];
#pragma unroll
    for (int mt = 0; mt < 4; ++mt) acc[mt] = (f32x4){0.f, 0.f, 0.f, 0.f};
#pragma unroll 2
    for (int ks = 0; ks < 32; ++ks) {
        unsigned int bits = bw32[brow + ks];
        unsigned int byt = (bits >> (quad * 8)) & 0xFFu;
        V16 bf; bf.u = lut[byt];
#pragma unroll
        for (int mt = 0; mt < 4; ++mt) {
            V16 ah, al;
            ah.u = *(const uint4*)(Gt1h + goff[mt] + ks * 16);
            al.u = *(const uint4*)(Gt1l + goff[mt] + ks * 16);
            acc[mt] = __builtin_amdgcn_mfma_f32_16x16x32_bf16(ah.s, bf.s, acc[mt], 0, 0, 0);
            acc[mt] = __builtin_amdgcn_mfma_f32_16x16x32_bf16(al.s, bf.s, acc[mt], 0, 0, 0);
        }
    }
    const int node = node0 + nt * 16 + n;
    const int s = blockIdx.y;
#pragma unroll
    for (int mt = 0; mt < 4; ++mt)
        *(f32x4*)&num1p[((size_t)s * NN + node) * 64 + mt * 16 + quad * 4] = acc[mt];
}

// ---------------------------------------------------------------------------
// den[i] = sum_j bit(i,j)*u[j]. One wave per row.
// ---------------------------------------------------------------------------
__global__ __launch_bounds__(256) void k_den(const unsigned long long* __restrict__ Wb64,
                                             const float* __restrict__ u,
                                             float* __restrict__ den) {
    const int tid = threadIdx.x, wv = tid >> 6, lane = tid & 63;
    const int row = blockIdx.x * 4 + wv;
    float s = 0.f;
    for (int w = 0; w < 128; ++w) {
        unsigned long long bits = Wb64[(size_t)row * 128 + w];
        float uv = u[w * 64 + lane];
        s += ((bits >> lane) & 1ull) ? uv : 0.f;
    }
#pragma unroll
    for (int off = 32; off; off >>= 1) s += __shfl_down(s, off);
    if (lane == 0) den[row] = s;
}

// ---------------------------------------------------------------------------
// K4: layer-1 epilogue + layer-2 prep. 32 nodes/block; Z1 = num/den,
// out1 = elu(Z1@W21+b), H2 = out1@Wg2, u2 = exp(H2.a2dst), G2^T hi/lo out.
// ---------------------------------------------------------------------------
__global__ __launch_bounds__(256) void k_ep1(const float* __restrict__ num1p,
                                             const float* __restrict__ den1,
                                             const float* __restrict__ W21,
                                             const float* __restrict__ b21,
                                             const float* __restrict__ Wg2,
                                             const float* __restrict__ a2,
                                             unsigned int* __restrict__ Gt2h,
                                             unsigned int* __restrict__ Gt2l,
                                             float* __restrict__ u2) {
    __shared__ float zsh[4][64];
    __shared__ float osh[4][64];
    __shared__ unsigned int g2sh[32][33];   // [feat][node-in-block]
    const int tid = threadIdx.x, wv = tid >> 6, lane = tid & 63;
    const int node0 = blockIdx.x * 32;
    for (int it = 0; it < 8; ++it) {
        const int node = node0 + wv * 8 + it;
        float sacc = 0.f;
#pragma unroll
        for (int sp = 0; sp < 8; ++sp)
            sacc += num1p[((size_t)sp * NN + node) * 64 + lane];
        zsh[wv][lane] = sacc / den1[node];
        __syncthreads();
        float o = b21[lane];
        for (int c = 0; c < 64; ++c) o += zsh[wv][c] * W21[c * 64 + lane];
        o = elu_f(o);
        osh[wv][lane] = o;
        __syncthreads();
        const int l32 = lane & 31;
        float h = 0.f;
        for (int c = 0; c < 64; ++c) h += osh[wv][c] * Wg2[c * 32 + l32];
        float p = (lane < 32) ? h * a2[32 + l32] : 0.f;
#pragma unroll
        for (int off = 32; off; off >>= 1) p += __shfl_down(p, off);
        float d2 = __shfl(p, 0);
        float uu = expf(d2);
        if (lane == 0) u2[node] = uu;
        if (lane < 32) g2sh[l32][wv * 8 + it] = split_pack(uu * h);
        __syncthreads();
    }
    if (tid < 64) {
        const int f = tid & 31, half = tid >> 5;
        unsigned int v[32];
#pragma unroll
        for (int j = 0; j < 32; ++j) v[j] = g2sh[f][j];
        unsigned int* dst = (half ? Gt2l : Gt2h) + f * 4096 + blockIdx.x * 16;
        uint4* D4 = (uint4*)dst;
#pragma unroll
        for (int i = 0; i < 4; ++i) {
            uint4 w;
            if (half == 0) {
                w.x = (v[i*8+0] >> 16) | (v[i*8+1] & 0xFFFF0000u);
                w.y = (v[i*8+2] >> 16) | (v[i*8+3] & 0xFFFF0000u);
                w.z = (v[i*8+4] >> 16) | (v[i*8+5] & 0xFFFF0000u);
                w.w = (v[i*8+6] >> 16) | (v[i*8+7] & 0xFFFF0000u);
            } else {
                w.x = (v[i*8+0] & 0xFFFFu) | (v[i*8+1] << 16);
                w.y = (v[i*8+2] & 0xFFFFu) | (v[i*8+3] << 16);
                w.z = (v[i*8+4] & 0xFFFFu) | (v[i*8+5] << 16);
                w.w = (v[i*8+6] & 0xFFFFu) | (v[i*8+7] << 16);
            }
            D4[i] = w;
        }
    }
}

// ---------------------------------------------------------------------------
// K5: layer-2 MFMA (M=32). Bits staged coalesced from global Wb64 -> padded
// LDS; same fragment scheme as k_attn1.
// ---------------------------------------------------------------------------
__global__ __launch_bounds__(256) void k_attn2(const unsigned long long* __restrict__ Wb64,
                                               const unsigned int* __restrict__ Gt2h,
                                               const unsigned int* __restrict__ Gt2l,
                                               float* __restrict__ num2p) {
    __shared__ uint4 lut[256];
    __shared__ unsigned long long bwp[64 * 17];
    const int tid = threadIdx.x, wv = tid >> 6, lane = tid & 63;
    const int node0 = blockIdx.x * 64;
    const int kbase = blockIdx.y * 1024;
    build_lut(lut, tid);
    {
        const int r = tid >> 2, part = tid & 3;
        const unsigned long long* src =
            Wb64 + (size_t)(node0 + r) * 128 + (kbase >> 6) + part * 4;
#pragma unroll
        for (int q = 0; q < 4; ++q) bwp[r * 17 + part * 4 + q] = src[q];
    }
    __syncthreads();
    const int n = lane & 15, quad = lane >> 4;
    const int nt = wv;
    const unsigned int* bw32 = (const unsigned int*)bwp;
    const int brow = (nt * 16 + n) * 34;
    size_t goff[2];
#pragma unroll
    for (int mt = 0; mt < 2; ++mt)
        goff[mt] = (size_t)(mt * 16 + n) * 4096 + (kbase >> 1) + quad * 4;
    f32x4 acc[2];
#pragma unroll
    for (int mt = 0; mt < 2; ++mt) acc[mt] = (f32x4){0.f, 0.f, 0.f, 0.f};
#pragma unroll 2
    for (int ks = 0; ks < 32; ++ks) {
        unsigned int bits = bw32[brow + ks];
        unsigned int byt = (bits >> (quad * 8)) & 0xFFu;
        V16 bf; bf.u = lut[byt];
#pragma unroll
        for (int mt = 0; mt < 2; ++mt) {
            V16 ah, al;
            ah.u = *(const uint4*)(Gt2h + goff[mt] + ks * 16);
            al.u = *(const uint4*)(Gt2l + goff[mt] + ks * 16);
            acc[mt] = __builtin_amdgcn_mfma_f32_16x16x32_bf16(ah.s, bf.s, acc[mt], 0, 0, 0);
            acc[mt] = __builtin_amdgcn_mfma_f32_16x16x32_bf16(al.s, bf.s, acc[mt], 0, 0, 0);
        }
    }
    const int node = node0 + nt * 16 + n;
    const int s = blockIdx.y;
#pragma unroll
    for (int mt = 0; mt < 2; ++mt)
        *(f32x4*)&num2p[((size_t)s * NN + node) * 32 + mt * 16 + quad * 4] = acc[mt];
}

// ---------------------------------------------------------------------------
// K6: layer-2 epilogue + column partials for mean.
// ---------------------------------------------------------------------------
__global__ __launch_bounds__(256) void k_ep2(const float* __restrict__ num2p,
                                             const float* __restrict__ den2,
                                             const float* __restrict__ W22,
                                             const float* __restrict__ b22,
                                             float* __restrict__ gpart) {
    __shared__ float zsh[4][32];
    __shared__ float gsh[4][64];
    const int tid = threadIdx.x, wv = tid >> 6, lane = tid & 63;
    float greg = 0.f;
    for (int it = 0; it < 2; ++it) {
        const int row = blockIdx.x * 8 + wv * 2 + it;
        if (lane < 32) {
            float s = 0.f;
#pragma unroll
            for (int sp = 0; sp < 8; ++sp)
                s += num2p[((size_t)sp * NN + row) * 32 + lane];
            zsh[wv][lane] = s / den2[row];
        }
        __syncthreads();
        float o = b22[lane];
        for (int c = 0; c < 32; ++c) o += zsh[wv][c] * W22[c * 64 + lane];
        greg += elu_f(o);
        __syncthreads();
    }
    gsh[wv][lane] = greg;
    __syncthreads();
    if (tid < 64)
        gpart[(size_t)blockIdx.x * 64 + tid] =
            gsh[0][tid] + gsh[1][tid] + gsh[2][tid] + gsh[3][tid];
}

// ---------------------------------------------------------------------------
// K7: mean + MLP head.
// ---------------------------------------------------------------------------
__global__ __launch_bounds__(64) void k_head(const float* __restrict__ gpart,
                                             const float* __restrict__ M1,
                                             const float* __restrict__ bm1,
                                             const float* __restrict__ M2,
                                             const float* __restrict__ bm2,
                                             float* __restrict__ outp) {
    __shared__ float gsh[64];
    __shared__ float hsh[64];
    const int tid = threadIdx.x;
    float s = 0.f;
    for (int b = 0; b < 1024; ++b) s += gpart[b * 64 + tid];
    gsh[tid] = s * (1.0f / 8192.0f);
    __syncthreads();
    float h = bm1[tid];
    for (int c = 0; c < 64; ++c) h += gsh[c] * M1[c * 64 + tid];
    hsh[tid] = h > 0.f ? h : 0.f;
    __syncthreads();
    if (tid < 2) {
        float o = bm2[tid];
        for (int j = 0; j < 64; ++j) o += hsh[j] * M2[j * 2 + tid];
        outp[tid] = o;
    }
}

// ---------------------------------------------------------------------------
extern "C" void kernel_launch(void* const* d_in, const int* in_sizes, int n_in,
                              void* d_out, int out_size, void* d_ws, size_t ws_size,
                              hipStream_t stream) {
    const float* X   = (const float*)d_in[0];
    const int*   A   = (const int*)  d_in[1];
    const float* W1  = (const float*)d_in[2];
    const float* a1  = (const float*)d_in[3];
    const float* W21 = (const float*)d_in[4];
    const float* b21 = (const float*)d_in[5];
    const float* Wg2 = (const float*)d_in[6];
    const float* a2  = (const float*)d_in[7];
    const float* W22 = (const float*)d_in[8];
    const float* b22 = (const float*)d_in[9];
    const float* M1  = (const float*)d_in[10];
    const float* bm1 = (const float*)d_in[11];
    const float* M2  = (const float*)d_in[12];
    const float* bm2 = (const float*)d_in[13];
    float* out = (float*)d_out;

    char* ws = (char*)d_ws;
    unsigned long long* Wb64 = (unsigned long long*)(ws + OFF_WBITS);
    unsigned int* Gt1h = (unsigned int*)(ws + OFF_GT1H);
    unsigned int* Gt1l = (unsigned int*)(ws + OFF_GT1L);
    unsigned int* Gt2h = (unsigned int*)(ws + OFF_GT2H);
    unsigned int* Gt2l = (unsigned int*)(ws + OFF_GT2L);
    float* u1    = (float*)(ws + OFF_U1);
    float* den1  = (float*)(ws + OFF_DEN1);
    float* u2    = (float*)(ws + OFF_U2);
    float* den2  = (float*)(ws + OFF_DEN2);
    float* gpart = (float*)(ws + OFF_GPART);
    float* nump  = (float*)(ws + OFF_NUMP);

    k_xw1  <<<256, 256, 0, stream>>>(X, W1, a1, Gt1h, Gt1l, u1);
    k_attn1<<<dim3(128, 8), 256, 0, stream>>>(A, Gt1h, Gt1l, Wb64, nump);
    k_den  <<<2048, 256, 0, stream>>>(Wb64, u1, den1);
    k_ep1  <<<256, 256, 0, stream>>>(nump, den1, W21, b21, Wg2, a2, Gt2h, Gt2l, u2);
    k_den  <<<2048, 256, 0, stream>>>(Wb64, u2, den2);
    k_attn2<<<dim3(128, 8), 256, 0, stream>>>(Wb64, Gt2h, Gt2l, nump);
    k_ep2  <<<1024, 256, 0, stream>>>(nump, den2, W22, b22, gpart);
    k_head <<<1, 64, 0, stream>>>(gpart, M1, bm1, M2, bm2, out);
}

// Round 3
// 621.707 us; speedup vs baseline: 2.0218x; 1.2637x over previous
//
#include <hip/hip_runtime.h>

// ============================================================================
// GAT classifier, N=8192. Softmax cancels the source term:
//   Z = (A @ (u*H)) / (A @ u),  u = exp(H @ a_dst).
// Round 3:
//  - k_pack: standalone A->bitmask streamer (int4 loads, LDS ushort repack,
//    fused den1 = A@u1). A read from HBM exactly once.
//  - Gt stored PRE-TILED in MFMA A-fragment order: one fragment load is
//    base + lane*16B (contiguous 1KB/wave) -- kills the 16-way scatter.
//  - den2 folded into layer-2 MFMA as feature row 32 (M=48, mt=2 tile holds
//    u2 in row 0, zeros elsewhere). Both k_den launches removed.
//  - ep1/ep2 widened (512-thread blocks, weights in LDS).
// ============================================================================

#define NN 8192

typedef __attribute__((ext_vector_type(8))) short s16x8;   // 8 bf16 (4 VGPR)
typedef __attribute__((ext_vector_type(4))) float f32x4;   // MFMA C/D
union V16 { uint4 u; s16x8 s; };

// ---- workspace layout ----
static constexpr size_t OFF_WBITS = 0;                                  // 8 MB bitmask
static constexpr size_t OFF_GT1H  = (size_t)8 << 20;                    // 1 MB Gt1 hi (tiled)
static constexpr size_t OFF_GT1L  = (size_t)9 << 20;                    // 1 MB Gt1 lo
static constexpr size_t OFF_U1    = (size_t)10 << 20;
static constexpr size_t OFF_DEN1  = ((size_t)10 << 20) + 32 * 1024;
static constexpr size_t OFF_U2    = ((size_t)10 << 20) + 64 * 1024;
static constexpr size_t OFF_GT2H  = ((size_t)10 << 20) + 128 * 1024;    // 768 KB Gt2 hi (tiled, M=48)
static constexpr size_t OFF_GT2L  = ((size_t)10 << 20) + 896 * 1024;    // 768 KB Gt2 lo
static constexpr size_t OFF_GPART = ((size_t)11 << 20) + 768 * 1024;    // 256 KB -> ends at 12MB
static constexpr size_t OFF_NUMP  = (size_t)12 << 20;                   // 16 MB partials

__device__ __forceinline__ float elu_f(float x) {
    return x > 0.f ? x : expm1f(x);
}
__device__ __forceinline__ unsigned int bf16_rne(float x) {
    unsigned int u = __float_as_uint(x);
    return (u + 0x7FFFu + ((u >> 16) & 1u)) >> 16;
}
// pack (hi<<16)|lo where x ~= bf16(hi) + bf16(lo)
__device__ __forceinline__ unsigned int split_pack(float g) {
    unsigned int hi = bf16_rne(g);
    float fhi = __uint_as_float(hi << 16);
    unsigned int lo = bf16_rne(g - fhi);
    return (hi << 16) | lo;
}

// ---------------------------------------------------------------------------
// K1: H1 = X @ W1 ; u1 = exp(H1 @ a1[64:]); Gt1 = u1*H1 in TILED fragment
// layout: u32 index ((mt*256 + kt)*64 + lane)*4 + q holds bf16 pair of nodes
// (kt*32 + quad*8 + 2q, +1) for feature mt*16 + (lane&15). Block = kt (32 nodes).
// ---------------------------------------------------------------------------
__global__ __launch_bounds__(256) void k_xw1(const float* __restrict__ X,
                                             const float* __restrict__ W1,
                                             const float* __restrict__ a1,
                                             unsigned int* __restrict__ Gt1h,
                                             unsigned int* __restrict__ Gt1l,
                                             float* __restrict__ u1) {
    __shared__ float Xt[32][65];
    __shared__ float red[32][8];
    __shared__ float us[32];
    __shared__ unsigned int Gsh[64][33];   // packed hi|lo, [feat][node]
    const int tid = threadIdx.x;
    const int row = tid & 31, cg = tid >> 5;
    const int row0 = blockIdx.x * 32;
    float acc[8];
#pragma unroll
    for (int i = 0; i < 8; ++i) acc[i] = 0.f;
    const float4* X4 = (const float4*)X;
    for (int k0 = 0; k0 < 768; k0 += 64) {
        __syncthreads();
#pragma unroll
        for (int f = tid; f < 512; f += 256) {
            int r = f >> 4, q = f & 15;
            float4 v = X4[(size_t)(row0 + r) * 192 + (k0 >> 2) + q];
            Xt[r][q * 4 + 0] = v.x; Xt[r][q * 4 + 1] = v.y;
            Xt[r][q * 4 + 2] = v.z; Xt[r][q * 4 + 3] = v.w;
        }
        __syncthreads();
        const float4* W4 = (const float4*)(W1 + (size_t)k0 * 64);
        for (int kk = 0; kk < 64; ++kk) {
            float x = Xt[row][kk];
            float4 w0 = W4[kk * 16 + cg * 2];
            float4 w1 = W4[kk * 16 + cg * 2 + 1];
            acc[0] += x * w0.x; acc[1] += x * w0.y;
            acc[2] += x * w0.z; acc[3] += x * w0.w;
            acc[4] += x * w1.x; acc[5] += x * w1.y;
            acc[6] += x * w1.z; acc[7] += x * w1.w;
        }
    }
    float p = 0.f;
#pragma unroll
    for (int i = 0; i < 8; ++i) p += acc[i] * a1[64 + cg * 8 + i];
    red[row][cg] = p;
    __syncthreads();
    if (tid < 32) {
        float d = 0.f;
#pragma unroll
        for (int g = 0; g < 8; ++g) d += red[tid][g];
        float uv = expf(d);
        u1[row0 + tid] = uv;
        us[tid] = uv;
    }
    __syncthreads();
    float uv = us[row];
#pragma unroll
    for (int i = 0; i < 8; ++i)
        Gsh[cg * 8 + i][row] = split_pack(acc[i] * uv);
    __syncthreads();
    // tiled writer: 256 threads = 4 mt x 64 lanes
    {
        const int mt = tid >> 6, lane = tid & 63;
        const int feat = mt * 16 + (lane & 15), quad = lane >> 4;
        uint4 hv, lv;
        unsigned int g0, g1;
#define PACK_Q(Q, FX, FY)                                        \
        g0 = Gsh[feat][quad * 8 + 2 * Q];                        \
        g1 = Gsh[feat][quad * 8 + 2 * Q + 1];                    \
        hv.FX = (g0 >> 16) | (g1 & 0xFFFF0000u);                 \
        lv.FX = (g0 & 0xFFFFu) | (g1 << 16);
        PACK_Q(0, x, x) PACK_Q(1, y, y) PACK_Q(2, z, z) PACK_Q(3, w, w)
#undef PACK_Q
        size_t base = ((size_t)(mt * 256 + blockIdx.x) * 64 + lane) * 4;
        *(uint4*)(Gt1h + base) = hv;
        *(uint4*)(Gt1l + base) = lv;
    }
}

// ---------------------------------------------------------------------------
// K2: pack A -> bitmask + den1 = A @ u1. Block = 8 rows; wave = 2 rows.
// Lane builds a 16-bit mask from 4x int4 loads, writes ushort to LDS;
// coalesced uint4 store phase. A read from HBM exactly once, 16B/lane.
// ---------------------------------------------------------------------------
__global__ __launch_bounds__(256) void k_pack(const int* __restrict__ A,
                                              const float* __restrict__ u1,
                                              unsigned int* __restrict__ Wb32,
                                              float* __restrict__ den1) {
    __shared__ unsigned short msh[8][512];   // 8 rows x 512 ushort = 8KB
    const int tid = threadIdx.x, wv = tid >> 6, lane = tid & 63;
    const int row0 = blockIdx.x * 8;
    float dsum0 = 0.f, dsum1 = 0.f;
    const int r0 = row0 + wv * 2, r1 = r0 + 1;
    for (int c = 0; c < 8; ++c) {
        const int j = c * 1024 + lane * 16;
        const int4* A0 = (const int4*)(A + (size_t)r0 * NN + j);
        const int4* A1 = (const int4*)(A + (size_t)r1 * NN + j);
        const float4* U4 = (const float4*)(u1 + j);
        int4 a0 = A0[0], a1 = A0[1], a2 = A0[2], a3 = A0[3];
        int4 b0 = A1[0], b1 = A1[1], b2 = A1[2], b3 = A1[3];
        float4 u0 = U4[0], u4 = U4[1], u8 = U4[2], uc = U4[3];
        unsigned int m0 = 0, m1 = 0;
#define DO4(AV, BV, UV, SH)                                            \
        m0 |= ((AV.x != 0) << (SH)) | ((AV.y != 0) << (SH + 1)) |      \
              ((AV.z != 0) << (SH + 2)) | ((AV.w != 0) << (SH + 3));   \
        m1 |= ((BV.x != 0) << (SH)) | ((BV.y != 0) << (SH + 1)) |      \
              ((BV.z != 0) << (SH + 2)) | ((BV.w != 0) << (SH + 3));   \
        dsum0 += (AV.x != 0 ? UV.x : 0.f) + (AV.y != 0 ? UV.y : 0.f) + \
                 (AV.z != 0 ? UV.z : 0.f) + (AV.w != 0 ? UV.w : 0.f);  \
        dsum1 += (BV.x != 0 ? UV.x : 0.f) + (BV.y != 0 ? UV.y : 0.f) + \
                 (BV.z != 0 ? UV.z : 0.f) + (BV.w != 0 ? UV.w : 0.f);
        DO4(a0, b0, u0, 0) DO4(a1, b1, u4, 4) DO4(a2, b2, u8, 8) DO4(a3, b3, uc, 12)
#undef DO4
        msh[wv * 2 + 0][c * 64 + lane] = (unsigned short)m0;
        msh[wv * 2 + 1][c * 64 + lane] = (unsigned short)m1;
    }
#pragma unroll
    for (int off = 32; off; off >>= 1) {
        dsum0 += __shfl_down(dsum0, off);
        dsum1 += __shfl_down(dsum1, off);
    }
    if (lane == 0) { den1[r0] = dsum0; den1[r1] = dsum1; }
    __syncthreads();
    {
        const int r = tid >> 5, i = tid & 31;
        const uint4* src = (const uint4*)&msh[r][0];
        uint4* dst = (uint4*)(Wb32 + (size_t)(row0 + r) * 256);
        dst[i] = src[i];
        dst[i + 32] = src[i + 32];
    }
}

// ---------------------------------------------------------------------------
// LUT: byte -> 8 packed bf16 {0,1}.
// ---------------------------------------------------------------------------
__device__ __forceinline__ void build_lut(uint4* lut, int tid) {
    unsigned int b = (unsigned int)tid;
    uint4 e;
    e.x = ((b & 1u)   ? 0x3F80u : 0u) | ((b & 2u)   ? 0x3F800000u : 0u);
    e.y = ((b & 4u)   ? 0x3F80u : 0u) | ((b & 8u)   ? 0x3F800000u : 0u);
    e.z = ((b & 16u)  ? 0x3F80u : 0u) | ((b & 32u)  ? 0x3F800000u : 0u);
    e.w = ((b & 64u)  ? 0x3F80u : 0u) | ((b & 128u) ? 0x3F800000u : 0u);
    lut[tid] = e;
}

// ---------------------------------------------------------------------------
// K3: layer-1 MFMA. grid (128 node-groups, 8 ksplits). Wave = n-tile,
// 4 m-tiles. Gt1 fragment loads are contiguous (tiled layout).
// ---------------------------------------------------------------------------
__global__ __launch_bounds__(256) void k_attn1(const unsigned int* __restrict__ Wb32,
                                               const unsigned int* __restrict__ Gt1h,
                                               const unsigned int* __restrict__ Gt1l,
                                               float* __restrict__ num1p) {
    __shared__ uint4 lut[256];
    __shared__ unsigned int bw[64 * 36];    // 64 rows x 32 u32, stride 36
    const int tid = threadIdx.x, wv = tid >> 6, lane = tid & 63;
    const int node0 = blockIdx.x * 64;
    const int kt0 = blockIdx.y * 32;        // k-chunk = 1024 nodes = 32 k-tiles
    build_lut(lut, tid);
    {
        const int r = tid >> 2, part = tid & 3;
        const uint4* src = (const uint4*)(Wb32 + (size_t)(node0 + r) * 256 + kt0 + part * 8);
        uint4 v0 = src[0], v1 = src[1];
        *(uint4*)&bw[r * 36 + part * 8] = v0;
        *(uint4*)&bw[r * 36 + part * 8 + 4] = v1;
    }
    __syncthreads();
    const int n = lane & 15, quad = lane >> 4;
    const int brow = (wv * 16 + n) * 36;
    f32x4 acc[4];
#pragma unroll
    for (int mt = 0; mt < 4; ++mt) acc[mt] = (f32x4){0.f, 0.f, 0.f, 0.f};
#pragma unroll 2
    for (int ks = 0; ks < 32; ++ks) {
        unsigned int bits = bw[brow + ks];
        unsigned int byt = (bits >> (quad * 8)) & 0xFFu;
        V16 bf; bf.u = lut[byt];
#pragma unroll
        for (int mt = 0; mt < 4; ++mt) {
            size_t base = ((size_t)(mt * 256 + kt0 + ks) * 64 + lane) * 4;
            V16 ah, al;
            ah.u = *(const uint4*)(Gt1h + base);
            al.u = *(const uint4*)(Gt1l + base);
            acc[mt] = __builtin_amdgcn_mfma_f32_16x16x32_bf16(ah.s, bf.s, acc[mt], 0, 0, 0);
            acc[mt] = __builtin_amdgcn_mfma_f32_16x16x32_bf16(al.s, bf.s, acc[mt], 0, 0, 0);
        }
    }
    const int node = node0 + wv * 16 + n;
    const int s = blockIdx.y;
#pragma unroll
    for (int mt = 0; mt < 4; ++mt)
        *(f32x4*)&num1p[((size_t)s * NN + node) * 64 + mt * 16 + quad * 4] = acc[mt];
}

// ---------------------------------------------------------------------------
// K4: layer-1 epilogue + layer-2 prep. 512 threads, 32 nodes/block (block =
// kt for the Gt2 tile writer). Weights in LDS. Writes Gt2 tiled with M=48:
// mt 0,1 = features, mt 2 = [u2; zeros] (den2 rides the MFMA).
// ---------------------------------------------------------------------------
__global__ __launch_bounds__(512) void k_ep1(const float* __restrict__ num1p,
                                             const float* __restrict__ den1,
                                             const float* __restrict__ W21,
                                             const float* __restrict__ b21,
                                             const float* __restrict__ Wg2,
                                             const float* __restrict__ a2,
                                             unsigned int* __restrict__ Gt2h,
                                             unsigned int* __restrict__ Gt2l,
                                             float* __restrict__ u2) {
    __shared__ float w21sh[64 * 64];
    __shared__ float wg2sh[64 * 32];
    __shared__ float zsh[8][64];
    __shared__ float osh[8][64];
    __shared__ unsigned int g2sh[32][33];
    __shared__ unsigned int u2sh[32];
    const int tid = threadIdx.x, wv = tid >> 6, lane = tid & 63;
    const int node0 = blockIdx.x * 32;
    {
        const float4* s4 = (const float4*)W21;
        float4* d4 = (float4*)w21sh;
        d4[tid] = s4[tid];
        d4[tid + 512] = s4[tid + 512];
        ((float4*)wg2sh)[tid] = ((const float4*)Wg2)[tid];
    }
    const float bb = b21[lane];
    const int l32 = lane & 31;
    const float a2v = (lane < 32) ? a2[32 + l32] : 0.f;
    __syncthreads();
    for (int it = 0; it < 4; ++it) {
        const int node = node0 + wv * 4 + it;
        float sacc = 0.f;
#pragma unroll
        for (int sp = 0; sp < 8; ++sp)
            sacc += num1p[((size_t)sp * NN + node) * 64 + lane];
        zsh[wv][lane] = sacc / den1[node];
        __syncthreads();
        float o0 = 0.f, o1 = 0.f, o2 = 0.f, o3 = 0.f;
        for (int c = 0; c < 64; c += 4) {
            o0 += zsh[wv][c + 0] * w21sh[(c + 0) * 64 + lane];
            o1 += zsh[wv][c + 1] * w21sh[(c + 1) * 64 + lane];
            o2 += zsh[wv][c + 2] * w21sh[(c + 2) * 64 + lane];
            o3 += zsh[wv][c + 3] * w21sh[(c + 3) * 64 + lane];
        }
        float o = elu_f(bb + ((o0 + o1) + (o2 + o3)));
        osh[wv][lane] = o;
        __syncthreads();
        float h0 = 0.f, h1 = 0.f;
        for (int c = 0; c < 64; c += 2) {
            h0 += osh[wv][c + 0] * wg2sh[(c + 0) * 32 + l32];
            h1 += osh[wv][c + 1] * wg2sh[(c + 1) * 32 + l32];
        }
        float hval = h0 + h1;
        float pp = hval * a2v;
#pragma unroll
        for (int off = 32; off; off >>= 1) pp += __shfl_down(pp, off);
        float d2 = __shfl(pp, 0);
        float uu = expf(d2);
        const int nodeloc = wv * 4 + it;
        if (lane == 0) {
            u2[node] = uu;
            u2sh[nodeloc] = split_pack(uu);
        }
        if (lane < 32) g2sh[l32][nodeloc] = split_pack(uu * hval);
        __syncthreads();
    }
    // tiled Gt2 writer: threads 0..191 = 3 mt x 64 lanes
    if (tid < 192) {
        const int mt = tid >> 6, lane2 = tid & 63;
        const int ml = lane2 & 15, quad = lane2 >> 4;
        uint4 hv, lv;
        unsigned int g0, g1;
#define PACK_Q(Q, F)                                                   \
        {                                                              \
            int j0 = quad * 8 + 2 * Q;                                 \
            if (mt < 2) { g0 = g2sh[mt * 16 + ml][j0];                 \
                          g1 = g2sh[mt * 16 + ml][j0 + 1]; }           \
            else if (ml == 0) { g0 = u2sh[j0]; g1 = u2sh[j0 + 1]; }    \
            else { g0 = 0; g1 = 0; }                                   \
            hv.F = (g0 >> 16) | (g1 & 0xFFFF0000u);                    \
            lv.F = (g0 & 0xFFFFu) | (g1 << 16);                        \
        }
        PACK_Q(0, x) PACK_Q(1, y) PACK_Q(2, z) PACK_Q(3, w)
#undef PACK_Q
        size_t base = ((size_t)(mt * 256 + blockIdx.x) * 64 + lane2) * 4;
        *(uint4*)(Gt2h + base) = hv;
        *(uint4*)(Gt2l + base) = lv;
    }
}

// ---------------------------------------------------------------------------
// K5: layer-2 MFMA, M=48 (feat 0..31 + den-row 32). Same scheme as k_attn1.
// ---------------------------------------------------------------------------
__global__ __launch_bounds__(256) void k_attn2(const unsigned int* __restrict__ Wb32,
                                               const unsigned int* __restrict__ Gt2h,
                                               const unsigned int* __restrict__ Gt2l,
                                               float* __restrict__ num2p) {
    __shared__ uint4 lut[256];
    __shared__ unsigned int bw[64 * 36];
    const int tid = threadIdx.x, wv = tid >> 6, lane = tid & 63;
    const int node0 = blockIdx.x * 64;
    const int kt0 = blockIdx.y * 32;
    build_lut(lut, tid);
    {
        const int r = tid >> 2, part = tid & 3;
        const uint4* src = (const uint4*)(Wb32 + (size_t)(node0 + r) * 256 + kt0 + part * 8);
        uint4 v0 = src[0], v1 = src[1];
        *(uint4*)&bw[r * 36 + part * 8] = v0;
        *(uint4*)&bw[r * 36 + part * 8 + 4] = v1;
    }
    __syncthreads();
    const int n = lane & 15, quad = lane >> 4;
    const int brow = (wv * 16 + n) * 36;
    f32x4 acc[3];
#pragma unroll
    for (int mt = 0; mt < 3; ++mt) acc[mt] = (f32x4){0.f, 0.f, 0.f, 0.f};
#pragma unroll 2
    for (int ks = 0; ks < 32; ++ks) {
        unsigned int bits = bw[brow + ks];
        unsigned int byt = (bits >> (quad * 8)) & 0xFFu;
        V16 bf; bf.u = lut[byt];
#pragma unroll
        for (int mt = 0; mt < 3; ++mt) {
            size_t base = ((size_t)(mt * 256 + kt0 + ks) * 64 + lane) * 4;
            V16 ah, al;
            ah.u = *(const uint4*)(Gt2h + base);
            al.u = *(const uint4*)(Gt2l + base);
            acc[mt] = __builtin_amdgcn_mfma_f32_16x16x32_bf16(ah.s, bf.s, acc[mt], 0, 0, 0);
            acc[mt] = __builtin_amdgcn_mfma_f32_16x16x32_bf16(al.s, bf.s, acc[mt], 0, 0, 0);
        }
    }
    const int node = node0 + wv * 16 + n;
    const int s = blockIdx.y;
#pragma unroll
    for (int mt = 0; mt < 3; ++mt)
        *(f32x4*)&num2p[((size_t)s * NN + node) * 48 + mt * 16 + quad * 4] = acc[mt];
}

// ---------------------------------------------------------------------------
// K6: layer-2 epilogue + column partials for mean. 512 threads, 8 rows/block,
// 1 row/wave. den2 comes from feature slot 32 of num2p.
// ---------------------------------------------------------------------------
__global__ __launch_bounds__(512) void k_ep2(const float* __restrict__ num2p,
                                             const float* __restrict__ W22,
                                             const float* __restrict__ b22,
                                             float* __restrict__ gpart) {
    __shared__ float w22sh[32 * 64];
    __shared__ float zsh[8][32];
    __shared__ float gsh[8][64];
    const int tid = threadIdx.x, wv = tid >> 6, lane = tid & 63;
    ((float4*)w22sh)[tid] = ((const float4*)W22)[tid];
    const float bb = b22[lane];
    __syncthreads();
    const int row = blockIdx.x * 8 + wv;
    float val = 0.f;
    if (lane < 33) {
#pragma unroll
        for (int sp = 0; sp < 8; ++sp)
            val += num2p[((size_t)sp * NN + row) * 48 + lane];
    }
    float den = __shfl(val, 32);
    if (lane < 32) zsh[wv][lane] = val / den;
    __syncthreads();
    float o0 = 0.f, o1 = 0.f;
    for (int c = 0; c < 32; c += 2) {
        o0 += zsh[wv][c + 0] * w22sh[(c + 0) * 64 + lane];
        o1 += zsh[wv][c + 1] * w22sh[(c + 1) * 64 + lane];
    }
    gsh[wv][lane] = elu_f(bb + o0 + o1);
    __syncthreads();
    if (tid < 64) {
        float s = 0.f;
#pragma unroll
        for (int w = 0; w < 8; ++w) s += gsh[w][tid];
        gpart[(size_t)blockIdx.x * 64 + tid] = s;
    }
}

// ---------------------------------------------------------------------------
// K7: mean + MLP head.
// ---------------------------------------------------------------------------
__global__ __launch_bounds__(64) void k_head(const float* __restrict__ gpart,
                                             const float* __restrict__ M1,
                                             const float* __restrict__ bm1,
                                             const float* __restrict__ M2,
                                             const float* __restrict__ bm2,
                                             float* __restrict__ outp) {
    __shared__ float gsh[64];
    __shared__ float hsh[64];
    const int tid = threadIdx.x;
    float s = 0.f;
    for (int b = 0; b < 1024; ++b) s += gpart[b * 64 + tid];
    gsh[tid] = s * (1.0f / 8192.0f);
    __syncthreads();
    float h = bm1[tid];
    for (int c = 0; c < 64; ++c) h += gsh[c] * M1[c * 64 + tid];
    hsh[tid] = h > 0.f ? h : 0.f;
    __syncthreads();
    if (tid < 2) {
        float o = bm2[tid];
        for (int j = 0; j < 64; ++j) o += hsh[j] * M2[j * 2 + tid];
        outp[tid] = o;
    }
}

// ---------------------------------------------------------------------------
extern "C" void kernel_launch(void* const* d_in, const int* in_sizes, int n_in,
                              void* d_out, int out_size, void* d_ws, size_t ws_size,
                              hipStream_t stream) {
    const float* X   = (const float*)d_in[0];
    const int*   A   = (const int*)  d_in[1];
    const float* W1  = (const float*)d_in[2];
    const float* a1  = (const float*)d_in[3];
    const float* W21 = (const float*)d_in[4];
    const float* b21 = (const float*)d_in[5];
    const float* Wg2 = (const float*)d_in[6];
    const float* a2  = (const float*)d_in[7];
    const float* W22 = (const float*)d_in[8];
    const float* b22 = (const float*)d_in[9];
    const float* M1  = (const float*)d_in[10];
    const float* bm1 = (const float*)d_in[11];
    const float* M2  = (const float*)d_in[12];
    const float* bm2 = (const float*)d_in[13];
    float* out = (float*)d_out;

    char* ws = (char*)d_ws;
    unsigned int* Wbits = (unsigned int*)(ws + OFF_WBITS);
    unsigned int* Gt1h  = (unsigned int*)(ws + OFF_GT1H);
    unsigned int* Gt1l  = (unsigned int*)(ws + OFF_GT1L);
    unsigned int* Gt2h  = (unsigned int*)(ws + OFF_GT2H);
    unsigned int* Gt2l  = (unsigned int*)(ws + OFF_GT2L);
    float* u1    = (float*)(ws + OFF_U1);
    float* den1  = (float*)(ws + OFF_DEN1);
    float* u2    = (float*)(ws + OFF_U2);
    float* gpart = (float*)(ws + OFF_GPART);
    float* nump  = (float*)(ws + OFF_NUMP);

    k_xw1  <<<256, 256, 0, stream>>>(X, W1, a1, Gt1h, Gt1l, u1);
    k_pack <<<1024, 256, 0, stream>>>(A, u1, Wbits, den1);
    k_attn1<<<dim3(128, 8), 256, 0, stream>>>(Wbits, Gt1h, Gt1l, nump);
    k_ep1  <<<256, 512, 0, stream>>>(nump, den1, W21, b21, Wg2, a2, Gt2h, Gt2l, u2);
    k_attn2<<<dim3(128, 8), 256, 0, stream>>>(Wbits, Gt2h, Gt2l, nump);
    k_ep2  <<<1024, 512, 0, stream>>>(nump, W22, b22, gpart);
    k_head <<<1, 64, 0, stream>>>(gpart, M1, bm1, M2, bm2, out);
}

// Round 4
// 591.121 us; speedup vs baseline: 2.1264x; 1.0517x over previous
//
#include <hip/hip_runtime.h>

// ============================================================================
// GAT classifier, N=8192. Softmax cancels the source term:
//   Z = (A @ (u*H)) / (A @ u),  u = exp(H @ a_dst).
// Round 4: occupancy/latency round.
//  - k_xw1: 512-thread blocks (4 waves/SIMD).
//  - attn kernels: 16-way ksplit -> 2048 blocks = 8 blocks/CU = 8 waves/SIMD.
//  - k_ep1: wave-local LDS (2 block barriers instead of 12).
//  - ~260us of dur_us is harness ws-poison/input-restore; kernel budget ~360.
// ============================================================================

#define NN 8192

typedef __attribute__((ext_vector_type(8))) short s16x8;   // 8 bf16 (4 VGPR)
typedef __attribute__((ext_vector_type(4))) float f32x4;   // MFMA C/D
union V16 { uint4 u; s16x8 s; };

// ---- workspace layout ----
static constexpr size_t OFF_WBITS = 0;                                  // 8 MB bitmask
static constexpr size_t OFF_GT1H  = (size_t)8 << 20;                    // 1 MB Gt1 hi (tiled)
static constexpr size_t OFF_GT1L  = (size_t)9 << 20;                    // 1 MB Gt1 lo
static constexpr size_t OFF_U1    = (size_t)10 << 20;
static constexpr size_t OFF_DEN1  = ((size_t)10 << 20) + 32 * 1024;
static constexpr size_t OFF_GT2H  = ((size_t)10 << 20) + 128 * 1024;    // 768 KB Gt2 hi (tiled, M=48)
static constexpr size_t OFF_GT2L  = ((size_t)10 << 20) + 896 * 1024;    // 768 KB Gt2 lo
static constexpr size_t OFF_GPART = ((size_t)11 << 20) + 768 * 1024;    // 256 KB
static constexpr size_t OFF_NUMP  = (size_t)12 << 20;                   // 32 MB partials

__device__ __forceinline__ float elu_f(float x) {
    return x > 0.f ? x : expm1f(x);
}
__device__ __forceinline__ unsigned int bf16_rne(float x) {
    unsigned int u = __float_as_uint(x);
    return (u + 0x7FFFu + ((u >> 16) & 1u)) >> 16;
}
// pack (hi<<16)|lo where x ~= bf16(hi) + bf16(lo)
__device__ __forceinline__ unsigned int split_pack(float g) {
    unsigned int hi = bf16_rne(g);
    float fhi = __uint_as_float(hi << 16);
    unsigned int lo = bf16_rne(g - fhi);
    return (hi << 16) | lo;
}

// ---------------------------------------------------------------------------
// K1: H1 = X @ W1 ; u1 = exp(H1 @ a1[64:]); Gt1 = u1*H1 in tiled MFMA
// A-fragment layout. 512 threads = 32 rows x 16 col-groups of 4.
// ---------------------------------------------------------------------------
__global__ __launch_bounds__(512) void k_xw1(const float* __restrict__ X,
                                             const float* __restrict__ W1,
                                             const float* __restrict__ a1,
                                             unsigned int* __restrict__ Gt1h,
                                             unsigned int* __restrict__ Gt1l,
                                             float* __restrict__ u1) {
    __shared__ float Xt[32][65];
    __shared__ float red[32][17];
    __shared__ float us[32];
    __shared__ unsigned int Gsh[64][33];   // packed hi|lo, [feat][node]
    const int tid = threadIdx.x;
    const int row = tid & 31, cg = tid >> 5;   // 16 col-groups * 4 cols
    const int row0 = blockIdx.x * 32;
    float acc[4];
#pragma unroll
    for (int i = 0; i < 4; ++i) acc[i] = 0.f;
    const float4* X4 = (const float4*)X;
    for (int k0 = 0; k0 < 768; k0 += 64) {
        __syncthreads();
        {
            int r = tid >> 4, q = tid & 15;
            float4 v = X4[(size_t)(row0 + r) * 192 + (k0 >> 2) + q];
            Xt[r][q * 4 + 0] = v.x; Xt[r][q * 4 + 1] = v.y;
            Xt[r][q * 4 + 2] = v.z; Xt[r][q * 4 + 3] = v.w;
        }
        __syncthreads();
        const float4* W4 = (const float4*)(W1 + (size_t)k0 * 64);
        for (int kk = 0; kk < 64; ++kk) {
            float x = Xt[row][kk];
            float4 w = W4[kk * 16 + cg];
            acc[0] += x * w.x; acc[1] += x * w.y;
            acc[2] += x * w.z; acc[3] += x * w.w;
        }
    }
    float p = 0.f;
#pragma unroll
    for (int i = 0; i < 4; ++i) p += acc[i] * a1[64 + cg * 4 + i];
    red[row][cg] = p;
    __syncthreads();
    if (tid < 32) {
        float d = 0.f;
#pragma unroll
        for (int g = 0; g < 16; ++g) d += red[tid][g];
        float uv = expf(d);
        u1[row0 + tid] = uv;
        us[tid] = uv;
    }
    __syncthreads();
    float uv = us[row];
#pragma unroll
    for (int i = 0; i < 4; ++i)
        Gsh[cg * 4 + i][row] = split_pack(acc[i] * uv);
    __syncthreads();
    if (tid < 256) {   // tiled writer: 4 mt x 64 lanes
        const int mt = tid >> 6, lane = tid & 63;
        const int feat = mt * 16 + (lane & 15), quad = lane >> 4;
        uint4 hv, lv;
        unsigned int g0, g1;
#define PACK_Q(Q, FX)                                            \
        g0 = Gsh[feat][quad * 8 + 2 * Q];                        \
        g1 = Gsh[feat][quad * 8 + 2 * Q + 1];                    \
        hv.FX = (g0 >> 16) | (g1 & 0xFFFF0000u);                 \
        lv.FX = (g0 & 0xFFFFu) | (g1 << 16);
        PACK_Q(0, x) PACK_Q(1, y) PACK_Q(2, z) PACK_Q(3, w)
#undef PACK_Q
        size_t base = ((size_t)(mt * 256 + blockIdx.x) * 64 + lane) * 4;
        *(uint4*)(Gt1h + base) = hv;
        *(uint4*)(Gt1l + base) = lv;
    }
}

// ---------------------------------------------------------------------------
// K2: pack A -> bitmask + den1 = A @ u1. Block = 8 rows; wave = 2 rows.
// A read from HBM exactly once, 16B/lane.
// ---------------------------------------------------------------------------
__global__ __launch_bounds__(256) void k_pack(const int* __restrict__ A,
                                              const float* __restrict__ u1,
                                              unsigned int* __restrict__ Wb32,
                                              float* __restrict__ den1) {
    __shared__ unsigned short msh[8][512];   // 8 rows x 512 ushort = 8KB
    const int tid = threadIdx.x, wv = tid >> 6, lane = tid & 63;
    const int row0 = blockIdx.x * 8;
    float dsum0 = 0.f, dsum1 = 0.f;
    const int r0 = row0 + wv * 2, r1 = r0 + 1;
    for (int c = 0; c < 8; ++c) {
        const int j = c * 1024 + lane * 16;
        const int4* A0 = (const int4*)(A + (size_t)r0 * NN + j);
        const int4* A1 = (const int4*)(A + (size_t)r1 * NN + j);
        const float4* U4 = (const float4*)(u1 + j);
        int4 a0 = A0[0], a1 = A0[1], a2 = A0[2], a3 = A0[3];
        int4 b0 = A1[0], b1 = A1[1], b2 = A1[2], b3 = A1[3];
        float4 u0 = U4[0], u4 = U4[1], u8 = U4[2], uc = U4[3];
        unsigned int m0 = 0, m1 = 0;
#define DO4(AV, BV, UV, SH)                                            \
        m0 |= ((AV.x != 0) << (SH)) | ((AV.y != 0) << (SH + 1)) |      \
              ((AV.z != 0) << (SH + 2)) | ((AV.w != 0) << (SH + 3));   \
        m1 |= ((BV.x != 0) << (SH)) | ((BV.y != 0) << (SH + 1)) |      \
              ((BV.z != 0) << (SH + 2)) | ((BV.w != 0) << (SH + 3));   \
        dsum0 += (AV.x != 0 ? UV.x : 0.f) + (AV.y != 0 ? UV.y : 0.f) + \
                 (AV.z != 0 ? UV.z : 0.f) + (AV.w != 0 ? UV.w : 0.f);  \
        dsum1 += (BV.x != 0 ? UV.x : 0.f) + (BV.y != 0 ? UV.y : 0.f) + \
                 (BV.z != 0 ? UV.z : 0.f) + (BV.w != 0 ? UV.w : 0.f);
        DO4(a0, b0, u0, 0) DO4(a1, b1, u4, 4) DO4(a2, b2, u8, 8) DO4(a3, b3, uc, 12)
#undef DO4
        msh[wv * 2 + 0][c * 64 + lane] = (unsigned short)m0;
        msh[wv * 2 + 1][c * 64 + lane] = (unsigned short)m1;
    }
#pragma unroll
    for (int off = 32; off; off >>= 1) {
        dsum0 += __shfl_down(dsum0, off);
        dsum1 += __shfl_down(dsum1, off);
    }
    if (lane == 0) { den1[r0] = dsum0; den1[r1] = dsum1; }
    __syncthreads();
    {
        const int r = tid >> 5, i = tid & 31;
        const uint4* src = (const uint4*)&msh[r][0];
        uint4* dst = (uint4*)(Wb32 + (size_t)(row0 + r) * 256);
        dst[i] = src[i];
        dst[i + 32] = src[i + 32];
    }
}

// ---------------------------------------------------------------------------
// LUT: byte -> 8 packed bf16 {0,1}.
// ---------------------------------------------------------------------------
__device__ __forceinline__ void build_lut(uint4* lut, int tid) {
    unsigned int b = (unsigned int)(tid & 255);
    uint4 e;
    e.x = ((b & 1u)   ? 0x3F80u : 0u) | ((b & 2u)   ? 0x3F800000u : 0u);
    e.y = ((b & 4u)   ? 0x3F80u : 0u) | ((b & 8u)   ? 0x3F800000u : 0u);
    e.z = ((b & 16u)  ? 0x3F80u : 0u) | ((b & 32u)  ? 0x3F800000u : 0u);
    e.w = ((b & 64u)  ? 0x3F80u : 0u) | ((b & 128u) ? 0x3F800000u : 0u);
    if (tid < 256) lut[tid] = e;
}

// ---------------------------------------------------------------------------
// K3: layer-1 MFMA. grid (128 node-groups, 16 ksplits) = 2048 blocks
// (8 blocks/CU, 8 waves/SIMD). Wave = n-tile, 4 m-tiles.
// ---------------------------------------------------------------------------
__global__ __launch_bounds__(256) void k_attn1(const unsigned int* __restrict__ Wb32,
                                               const unsigned int* __restrict__ Gt1h,
                                               const unsigned int* __restrict__ Gt1l,
                                               float* __restrict__ num1p) {
    __shared__ uint4 lut[256];
    __shared__ unsigned int bw[64 * 20];    // 64 rows x 16 u32, stride 20
    const int tid = threadIdx.x, wv = tid >> 6, lane = tid & 63;
    const int node0 = blockIdx.x * 64;
    const int kt0 = blockIdx.y * 16;        // k-chunk = 512 nodes = 16 k-tiles
    build_lut(lut, tid);
    {
        const int r = tid >> 2, part = tid & 3;
        const uint4* src = (const uint4*)(Wb32 + (size_t)(node0 + r) * 256 + kt0 + part * 4);
        *(uint4*)&bw[r * 20 + part * 4] = src[0];
    }
    __syncthreads();
    const int n = lane & 15, quad = lane >> 4;
    const int brow = (wv * 16 + n) * 20;
    f32x4 acc[4];
#pragma unroll
    for (int mt = 0; mt < 4; ++mt) acc[mt] = (f32x4){0.f, 0.f, 0.f, 0.f};
#pragma unroll 2
    for (int ks = 0; ks < 16; ++ks) {
        unsigned int bits = bw[brow + ks];
        unsigned int byt = (bits >> (quad * 8)) & 0xFFu;
        V16 bf; bf.u = lut[byt];
#pragma unroll
        for (int mt = 0; mt < 4; ++mt) {
            size_t base = ((size_t)(mt * 256 + kt0 + ks) * 64 + lane) * 4;
            V16 ah, al;
            ah.u = *(const uint4*)(Gt1h + base);
            al.u = *(const uint4*)(Gt1l + base);
            acc[mt] = __builtin_amdgcn_mfma_f32_16x16x32_bf16(ah.s, bf.s, acc[mt], 0, 0, 0);
            acc[mt] = __builtin_amdgcn_mfma_f32_16x16x32_bf16(al.s, bf.s, acc[mt], 0, 0, 0);
        }
    }
    const int node = node0 + wv * 16 + n;
    const int s = blockIdx.y;
#pragma unroll
    for (int mt = 0; mt < 4; ++mt)
        *(f32x4*)&num1p[((size_t)s * NN + node) * 64 + mt * 16 + quad * 4] = acc[mt];
}

// ---------------------------------------------------------------------------
// K4: layer-1 epilogue + layer-2 prep. Wave-local (2 block barriers total).
// Writes Gt2 tiled with M=48: mt 0,1 = features, mt 2 = [u2; zeros].
// ---------------------------------------------------------------------------
__global__ __launch_bounds__(512) void k_ep1(const float* __restrict__ num1p,
                                             const float* __restrict__ den1,
                                             const float* __restrict__ W21,
                                             const float* __restrict__ b21,
                                             const float* __restrict__ Wg2,
                                             const float* __restrict__ a2,
                                             unsigned int* __restrict__ Gt2h,
                                             unsigned int* __restrict__ Gt2l) {
    __shared__ float w21sh[64 * 64];
    __shared__ float wg2sh[64 * 32];
    __shared__ float zsh[8][64];
    __shared__ float osh[8][64];
    __shared__ unsigned int g2sh[32][33];
    __shared__ unsigned int u2sh[32];
    const int tid = threadIdx.x, wv = tid >> 6, lane = tid & 63;
    const int node0 = blockIdx.x * 32;
    {
        const float4* s4 = (const float4*)W21;
        float4* d4 = (float4*)w21sh;
        d4[tid] = s4[tid];
        d4[tid + 512] = s4[tid + 512];
        ((float4*)wg2sh)[tid] = ((const float4*)Wg2)[tid];
    }
    const float bb = b21[lane];
    const int l32 = lane & 31;
    const float a2v = (lane < 32) ? a2[32 + l32] : 0.f;
    __syncthreads();
    for (int it = 0; it < 4; ++it) {
        const int node = node0 + wv * 4 + it;
        float sacc = 0.f;
#pragma unroll
        for (int sp = 0; sp < 16; ++sp)
            sacc += num1p[((size_t)sp * NN + node) * 64 + lane];
        zsh[wv][lane] = sacc / den1[node];
        __builtin_amdgcn_wave_barrier();
        float o0 = 0.f, o1 = 0.f, o2 = 0.f, o3 = 0.f;
        for (int c = 0; c < 64; c += 4) {
            o0 += zsh[wv][c + 0] * w21sh[(c + 0) * 64 + lane];
            o1 += zsh[wv][c + 1] * w21sh[(c + 1) * 64 + lane];
            o2 += zsh[wv][c + 2] * w21sh[(c + 2) * 64 + lane];
            o3 += zsh[wv][c + 3] * w21sh[(c + 3) * 64 + lane];
        }
        float o = elu_f(bb + ((o0 + o1) + (o2 + o3)));
        osh[wv][lane] = o;
        __builtin_amdgcn_wave_barrier();
        float h0 = 0.f, h1 = 0.f;
        for (int c = 0; c < 64; c += 2) {
            h0 += osh[wv][c + 0] * wg2sh[(c + 0) * 32 + l32];
            h1 += osh[wv][c + 1] * wg2sh[(c + 1) * 32 + l32];
        }
        float hval = h0 + h1;
        float pp = hval * a2v;
#pragma unroll
        for (int off = 32; off; off >>= 1) pp += __shfl_down(pp, off);
        float d2 = __shfl(pp, 0);
        float uu = expf(d2);
        const int nodeloc = wv * 4 + it;
        if (lane == 0) u2sh[nodeloc] = split_pack(uu);
        if (lane < 32) g2sh[l32][nodeloc] = split_pack(uu * hval);
    }
    __syncthreads();
    if (tid < 192) {   // tiled Gt2 writer: 3 mt x 64 lanes
        const int mt = tid >> 6, lane2 = tid & 63;
        const int ml = lane2 & 15, quad = lane2 >> 4;
        uint4 hv, lv;
        unsigned int g0, g1;
#define PACK_Q(Q, F)                                                   \
        {                                                              \
            int j0 = quad * 8 + 2 * Q;                                 \
            if (mt < 2) { g0 = g2sh[mt * 16 + ml][j0];                 \
                          g1 = g2sh[mt * 16 + ml][j0 + 1]; }           \
            else if (ml == 0) { g0 = u2sh[j0]; g1 = u2sh[j0 + 1]; }    \
            else { g0 = 0; g1 = 0; }                                   \
            hv.F = (g0 >> 16) | (g1 & 0xFFFF0000u);                    \
            lv.F = (g0 & 0xFFFFu) | (g1 << 16);                        \
        }
        PACK_Q(0, x) PACK_Q(1, y) PACK_Q(2, z) PACK_Q(3, w)
#undef PACK_Q
        size_t base = ((size_t)(mt * 256 + blockIdx.x) * 64 + lane2) * 4;
        *(uint4*)(Gt2h + base) = hv;
        *(uint4*)(Gt2l + base) = lv;
    }
}

// ---------------------------------------------------------------------------
// K5: layer-2 MFMA, M=48 (feat 0..31 + den-row 32). grid (128,16).
// ---------------------------------------------------------------------------
__global__ __launch_bounds__(256) void k_attn2(const unsigned int* __restrict__ Wb32,
                                               const unsigned int* __restrict__ Gt2h,
                                               const unsigned int* __restrict__ Gt2l,
                                               float* __restrict__ num2p) {
    __shared__ uint4 lut[256];
    __shared__ unsigned int bw[64 * 20];
    const int tid = threadIdx.x, wv = tid >> 6, lane = tid & 63;
    const int node0 = blockIdx.x * 64;
    const int kt0 = blockIdx.y * 16;
    build_lut(lut, tid);
    {
        const int r = tid >> 2, part = tid & 3;
        const uint4* src = (const uint4*)(Wb32 + (size_t)(node0 + r) * 256 + kt0 + part * 4);
        *(uint4*)&bw[r * 20 + part * 4] = src[0];
    }
    __syncthreads();
    const int n = lane & 15, quad = lane >> 4;
    const int brow = (wv * 16 + n) * 20;
    f32x4 acc[3];
#pragma unroll
    for (int mt = 0; mt < 3; ++mt) acc[mt] = (f32x4){0.f, 0.f, 0.f, 0.f};
#pragma unroll 2
    for (int ks = 0; ks < 16; ++ks) {
        unsigned int bits = bw[brow + ks];
        unsigned int byt = (bits >> (quad * 8)) & 0xFFu;
        V16 bf; bf.u = lut[byt];
#pragma unroll
        for (int mt = 0; mt < 3; ++mt) {
            size_t base = ((size_t)(mt * 256 + kt0 + ks) * 64 + lane) * 4;
            V16 ah, al;
            ah.u = *(const uint4*)(Gt2h + base);
            al.u = *(const uint4*)(Gt2l + base);
            acc[mt] = __builtin_amdgcn_mfma_f32_16x16x32_bf16(ah.s, bf.s, acc[mt], 0, 0, 0);
            acc[mt] = __builtin_amdgcn_mfma_f32_16x16x32_bf16(al.s, bf.s, acc[mt], 0, 0, 0);
        }
    }
    const int node = node0 + wv * 16 + n;
    const int s = blockIdx.y;
#pragma unroll
    for (int mt = 0; mt < 3; ++mt)
        *(f32x4*)&num2p[((size_t)s * NN + node) * 48 + mt * 16 + quad * 4] = acc[mt];
}

// ---------------------------------------------------------------------------
// K6: layer-2 epilogue + column partials for mean. 8 rows/block, 1 row/wave.
// ---------------------------------------------------------------------------
__global__ __launch_bounds__(512) void k_ep2(const float* __restrict__ num2p,
                                             const float* __restrict__ W22,
                                             const float* __restrict__ b22,
                                             float* __restrict__ gpart) {
    __shared__ float w22sh[32 * 64];
    __shared__ float zsh[8][32];
    __shared__ float gsh[8][64];
    const int tid = threadIdx.x, wv = tid >> 6, lane = tid & 63;
    ((float4*)w22sh)[tid] = ((const float4*)W22)[tid];
    const float bb = b22[lane];
    __syncthreads();
    const int row = blockIdx.x * 8 + wv;
    float val = 0.f;
    if (lane < 33) {
#pragma unroll
        for (int sp = 0; sp < 16; ++sp)
            val += num2p[((size_t)sp * NN + row) * 48 + lane];
    }
    float den = __shfl(val, 32);
    if (lane < 32) zsh[wv][lane] = val / den;
    __builtin_amdgcn_wave_barrier();
    float o0 = 0.f, o1 = 0.f;
    for (int c = 0; c < 32; c += 2) {
        o0 += zsh[wv][c + 0] * w22sh[(c + 0) * 64 + lane];
        o1 += zsh[wv][c + 1] * w22sh[(c + 1) * 64 + lane];
    }
    gsh[wv][lane] = elu_f(bb + o0 + o1);
    __syncthreads();
    if (tid < 64) {
        float s = 0.f;
#pragma unroll
        for (int w = 0; w < 8; ++w) s += gsh[w][tid];
        gpart[(size_t)blockIdx.x * 64 + tid] = s;
    }
}

// ---------------------------------------------------------------------------
// K7: mean + MLP head. 256 threads: 4-way partial over the 1024 gpart rows.
// ---------------------------------------------------------------------------
__global__ __launch_bounds__(256) void k_head(const float* __restrict__ gpart,
                                              const float* __restrict__ M1,
                                              const float* __restrict__ bm1,
                                              const float* __restrict__ M2,
                                              const float* __restrict__ bm2,
                                              float* __restrict__ outp) {
    __shared__ float part[4][64];
    __shared__ float gsh[64];
    __shared__ float hsh[64];
    const int tid = threadIdx.x, col = tid & 63, p = tid >> 6;
    float s = 0.f;
    for (int b = p * 256; b < p * 256 + 256; ++b)
        s += gpart[(size_t)b * 64 + col];
    part[p][col] = s;
    __syncthreads();
    if (tid < 64)
        gsh[tid] = (part[0][tid] + part[1][tid] + part[2][tid] + part[3][tid])
                   * (1.0f / 8192.0f);
    __syncthreads();
    if (tid < 64) {
        float h = bm1[tid];
        for (int c = 0; c < 64; ++c) h += gsh[c] * M1[c * 64 + tid];
        hsh[tid] = h > 0.f ? h : 0.f;
    }
    __syncthreads();
    if (tid < 2) {
        float o = bm2[tid];
        for (int j = 0; j < 64; ++j) o += hsh[j] * M2[j * 2 + tid];
        outp[tid] = o;
    }
}

// ---------------------------------------------------------------------------
extern "C" void kernel_launch(void* const* d_in, const int* in_sizes, int n_in,
                              void* d_out, int out_size, void* d_ws, size_t ws_size,
                              hipStream_t stream) {
    const float* X   = (const float*)d_in[0];
    const int*   A   = (const int*)  d_in[1];
    const float* W1  = (const float*)d_in[2];
    const float* a1  = (const float*)d_in[3];
    const float* W21 = (const float*)d_in[4];
    const float* b21 = (const float*)d_in[5];
    const float* Wg2 = (const float*)d_in[6];
    const float* a2  = (const float*)d_in[7];
    const float* W22 = (const float*)d_in[8];
    const float* b22 = (const float*)d_in[9];
    const float* M1  = (const float*)d_in[10];
    const float* bm1 = (const float*)d_in[11];
    const float* M2  = (const float*)d_in[12];
    const float* bm2 = (const float*)d_in[13];
    float* out = (float*)d_out;

    char* ws = (char*)d_ws;
    unsigned int* Wbits = (unsigned int*)(ws + OFF_WBITS);
    unsigned int* Gt1h  = (unsigned int*)(ws + OFF_GT1H);
    unsigned int* Gt1l  = (unsigned int*)(ws + OFF_GT1L);
    unsigned int* Gt2h  = (unsigned int*)(ws + OFF_GT2H);
    unsigned int* Gt2l  = (unsigned int*)(ws + OFF_GT2L);
    float* u1    = (float*)(ws + OFF_U1);
    float* den1  = (float*)(ws + OFF_DEN1);
    float* gpart = (float*)(ws + OFF_GPART);
    float* nump  = (float*)(ws + OFF_NUMP);

    k_xw1  <<<256, 512, 0, stream>>>(X, W1, a1, Gt1h, Gt1l, u1);
    k_pack <<<1024, 256, 0, stream>>>(A, u1, Wbits, den1);
    k_attn1<<<dim3(128, 16), 256, 0, stream>>>(Wbits, Gt1h, Gt1l, nump);
    k_ep1  <<<256, 512, 0, stream>>>(nump, den1, W21, b21, Wg2, a2, Gt2h, Gt2l);
    k_attn2<<<dim3(128, 16), 256, 0, stream>>>(Wbits, Gt2h, Gt2l, nump);
    k_ep2  <<<1024, 512, 0, stream>>>(nump, W22, b22, gpart);
    k_head <<<1, 256, 0, stream>>>(gpart, M1, bm1, M2, bm2, out);
}

// Round 5
// 512.413 us; speedup vs baseline: 2.4530x; 1.1536x over previous
//
#include <hip/hip_runtime.h>

// ============================================================================
// GAT classifier, N=8192. Softmax cancels the source term:
//   Z = (A @ (u*H)) / (A @ u),  u = exp(H @ a_dst).
// Round 5: L1-traffic elimination.
//  - attn kernels: wave = m-tile -> each Gt fragment through L1 once per
//    block (4x less); B-frag built from bits via VALU (no LDS LUT).
//  - xw1 -> MFMA GEMM: A = W1^T bf16 hi/lo (k_wsetup pre-tiles), B = X rows
//    split 3-way bf16 (fp32-grade, 5 MFMA terms), ksplit=4 -> Dp; k_xcomb
//    reduces, computes u1, writes Gt1 tiled.
// ============================================================================

#define NN 8192

typedef __attribute__((ext_vector_type(8))) short s16x8;   // 8 bf16 (4 VGPR)
typedef __attribute__((ext_vector_type(4))) float f32x4;   // MFMA C/D
union V16 { uint4 u; s16x8 s; };

// ---- workspace layout ----
static constexpr size_t OFF_WBITS = 0;                                  // 8 MB bitmask
static constexpr size_t OFF_GT1H  = (size_t)8 << 20;                    // 1 MB Gt1 hi (tiled)
static constexpr size_t OFF_GT1L  = (size_t)9 << 20;                    // 1 MB Gt1 lo
static constexpr size_t OFF_U1    = (size_t)10 << 20;
static constexpr size_t OFF_DEN1  = ((size_t)10 << 20) + 32 * 1024;
static constexpr size_t OFF_GT2H  = ((size_t)10 << 20) + 128 * 1024;    // 768 KB Gt2 hi (tiled, M=48)
static constexpr size_t OFF_GT2L  = ((size_t)10 << 20) + 896 * 1024;    // 768 KB Gt2 lo
static constexpr size_t OFF_GPART = ((size_t)11 << 20) + 768 * 1024;    // 256 KB
static constexpr size_t OFF_NUMP  = (size_t)12 << 20;                   // 32 MB partials
static constexpr size_t OFF_WTAH  = (size_t)44 << 20;                   // 96 KB W1^T tiled hi
static constexpr size_t OFF_WTAL  = ((size_t)44 << 20) + 128 * 1024;    // 96 KB lo
static constexpr size_t OFF_DP    = (size_t)45 << 20;                   // 8 MB xw1 partials

__device__ __forceinline__ float elu_f(float x) {
    return x > 0.f ? x : expm1f(x);
}
__device__ __forceinline__ unsigned int bf16_rne(float x) {
    unsigned int u = __float_as_uint(x);
    return (u + 0x7FFFu + ((u >> 16) & 1u)) >> 16;
}
// pack (hi<<16)|lo where x ~= bf16(hi) + bf16(lo)
__device__ __forceinline__ unsigned int split_pack(float g) {
    unsigned int hi = bf16_rne(g);
    float fhi = __uint_as_float(hi << 16);
    unsigned int lo = bf16_rne(g - fhi);
    return (hi << 16) | lo;
}
__device__ __forceinline__ void split3(float f, unsigned int& h, unsigned int& m,
                                       unsigned int& l) {
    h = bf16_rne(f);
    float fh = __uint_as_float(h << 16);
    float r1 = f - fh;
    m = bf16_rne(r1);
    float fm = __uint_as_float(m << 16);
    l = bf16_rne(r1 - fm);
}
// byte (8 adjacency bits) -> one fragment-quarter uint (2 bf16 {0,1})
__device__ __forceinline__ unsigned int bits2bf(unsigned int b2) {
    return (b2 & 1u) * 0x3F80u + (b2 & 2u) * 0x1FC00000u;
}

// ---------------------------------------------------------------------------
// K0: pre-tile W1^T into MFMA A-fragment order, bf16 hi/lo.
// WtA[(mt*24+kt)*64+lane] uint4: feat = mt*16+(lane&15), k = kt*32+quad*8+2q.
// ---------------------------------------------------------------------------
__global__ __launch_bounds__(256) void k_wsetup(const float* __restrict__ W1,
                                                unsigned int* __restrict__ WtAh,
                                                unsigned int* __restrict__ WtAl) {
    const int t = blockIdx.x * 256 + threadIdx.x;
    const int tile = t >> 6, lane = t & 63;
    const int mt = tile / 24, kt = tile % 24;
    const int feat = mt * 16 + (lane & 15), quad = lane >> 4;
    uint4 hv, lv;
    unsigned int h0, l0, h1, l1;
#define WQ(Q, F)                                                        \
    {                                                                   \
        int k0 = kt * 32 + quad * 8 + 2 * Q;                            \
        float w0 = W1[(size_t)k0 * 64 + feat];                          \
        float w1 = W1[(size_t)(k0 + 1) * 64 + feat];                    \
        h0 = bf16_rne(w0); l0 = bf16_rne(w0 - __uint_as_float(h0 << 16));\
        h1 = bf16_rne(w1); l1 = bf16_rne(w1 - __uint_as_float(h1 << 16));\
        hv.F = h0 | (h1 << 16);                                         \
        lv.F = l0 | (l1 << 16);                                         \
    }
    WQ(0, x) WQ(1, y) WQ(2, z) WQ(3, w)
#undef WQ
    size_t base = (size_t)((mt * 24 + kt) * 64 + lane) * 4;
    *(uint4*)(WtAh + base) = hv;
    *(uint4*)(WtAl + base) = lv;
}

// ---------------------------------------------------------------------------
// K1: H1 = X @ W1 on MFMA. D[feat][node] tiles. A = WtA (hi/lo), B = X rows
// split 3-way bf16 in-register. grid (128 node-groups of 64, 4 ksplits of 6kt).
// Wave = n-tile. 5 MFMA terms: XhWh, XmWh, XlWh, XhWl, XmWl.
// ---------------------------------------------------------------------------
__global__ __launch_bounds__(256) void k_xw1m(const float* __restrict__ X,
                                              const unsigned int* __restrict__ WtAh,
                                              const unsigned int* __restrict__ WtAl,
                                              float* __restrict__ Dp) {
    const int tid = threadIdx.x, wv = tid >> 6, lane = tid & 63;
    const int n = lane & 15, quad = lane >> 4;
    const int node = blockIdx.x * 64 + wv * 16 + n;
    const int ntg = blockIdx.x * 4 + wv;
    const int ks = blockIdx.y;
    f32x4 acc[4];
#pragma unroll
    for (int mt = 0; mt < 4; ++mt) acc[mt] = (f32x4){0.f, 0.f, 0.f, 0.f};
    const float4* X4 = (const float4*)X;
    for (int kk = 0; kk < 6; ++kk) {
        const int kt = ks * 6 + kk;
        float4 x01 = X4[(size_t)node * 192 + kt * 8 + quad * 2];
        float4 x23 = X4[(size_t)node * 192 + kt * 8 + quad * 2 + 1];
        float xf[8] = {x01.x, x01.y, x01.z, x01.w, x23.x, x23.y, x23.z, x23.w};
        V16 bh, bm, bl;
        unsigned int* bhp = (unsigned int*)&bh.u;
        unsigned int* bmp = (unsigned int*)&bm.u;
        unsigned int* blp = (unsigned int*)&bl.u;
#pragma unroll
        for (int q = 0; q < 4; ++q) {
            unsigned int h0, m0, l0, h1, m1, l1;
            split3(xf[2 * q], h0, m0, l0);
            split3(xf[2 * q + 1], h1, m1, l1);
            bhp[q] = h0 | (h1 << 16);
            bmp[q] = m0 | (m1 << 16);
            blp[q] = l0 | (l1 << 16);
        }
#pragma unroll
        for (int mt = 0; mt < 4; ++mt) {
            size_t base = (size_t)((mt * 24 + kt) * 64 + lane) * 4;
            V16 awh, awl;
            awh.u = *(const uint4*)(WtAh + base);
            awl.u = *(const uint4*)(WtAl + base);
            acc[mt] = __builtin_amdgcn_mfma_f32_16x16x32_bf16(awh.s, bh.s, acc[mt], 0, 0, 0);
            acc[mt] = __builtin_amdgcn_mfma_f32_16x16x32_bf16(awh.s, bm.s, acc[mt], 0, 0, 0);
            acc[mt] = __builtin_amdgcn_mfma_f32_16x16x32_bf16(awh.s, bl.s, acc[mt], 0, 0, 0);
            acc[mt] = __builtin_amdgcn_mfma_f32_16x16x32_bf16(awl.s, bh.s, acc[mt], 0, 0, 0);
            acc[mt] = __builtin_amdgcn_mfma_f32_16x16x32_bf16(awl.s, bm.s, acc[mt], 0, 0, 0);
        }
    }
#pragma unroll
    for (int mt = 0; mt < 4; ++mt)
        *(f32x4*)&Dp[(size_t)(((ks * 4 + mt) * 512 + ntg) * 64 + lane) * 4] = acc[mt];
}

// ---------------------------------------------------------------------------
// K1b: reduce Dp ksplits -> H1; u1 = exp(H1 @ a1[64:]); write Gt1 tiled
// (bf16 hi/lo) + u1. Block = 32 nodes (= one Gt k-tile).
// ---------------------------------------------------------------------------
__global__ __launch_bounds__(256) void k_xcomb(const float* __restrict__ Dp,
                                               const float* __restrict__ a1,
                                               unsigned int* __restrict__ Gt1h,
                                               unsigned int* __restrict__ Gt1l,
                                               float* __restrict__ u1) {
    __shared__ float Hsh[64][33];
    __shared__ float us[32];
    const int tid = threadIdx.x;
    if (tid < 128) {
        const int ntl = tid >> 6, lane = tid & 63;
        const int n = lane & 15, quad = lane >> 4;
        const int ntg = blockIdx.x * 2 + ntl;
        float dpart = 0.f;
#pragma unroll
        for (int mt = 0; mt < 4; ++mt) {
            float v[4] = {0.f, 0.f, 0.f, 0.f};
#pragma unroll
            for (int ksp = 0; ksp < 4; ++ksp) {
                const float* p = &Dp[(size_t)(((ksp * 4 + mt) * 512 + ntg) * 64 + lane) * 4];
                v[0] += p[0]; v[1] += p[1]; v[2] += p[2]; v[3] += p[3];
            }
#pragma unroll
            for (int r = 0; r < 4; ++r) {
                int feat = mt * 16 + quad * 4 + r;
                Hsh[feat][ntl * 16 + n] = v[r];
                dpart += v[r] * a1[64 + feat];
            }
        }
        dpart += __shfl_xor(dpart, 16);
        dpart += __shfl_xor(dpart, 32);
        float uu = expf(dpart);
        if (lane < 16) {
            us[ntl * 16 + lane] = uu;
            u1[blockIdx.x * 32 + ntl * 16 + lane] = uu;
        }
    }
    __syncthreads();
    {   // tiled writer: 4 mt x 64 lanes
        const int mt = tid >> 6, lane = tid & 63;
        const int feat = mt * 16 + (lane & 15), quad = lane >> 4;
        uint4 hv, lv;
        unsigned int g0, g1;
#define PACK_Q(Q, FX)                                                   \
        {                                                               \
            int j0 = quad * 8 + 2 * Q;                                  \
            g0 = split_pack(us[j0] * Hsh[feat][j0]);                    \
            g1 = split_pack(us[j0 + 1] * Hsh[feat][j0 + 1]);            \
            hv.FX = (g0 >> 16) | (g1 & 0xFFFF0000u);                    \
            lv.FX = (g0 & 0xFFFFu) | (g1 << 16);                        \
        }
        PACK_Q(0, x) PACK_Q(1, y) PACK_Q(2, z) PACK_Q(3, w)
#undef PACK_Q
        size_t base = ((size_t)(mt * 256 + blockIdx.x) * 64 + lane) * 4;
        *(uint4*)(Gt1h + base) = hv;
        *(uint4*)(Gt1l + base) = lv;
    }
}

// ---------------------------------------------------------------------------
// K2: pack A -> bitmask + den1 = A @ u1. A read from HBM exactly once.
// ---------------------------------------------------------------------------
__global__ __launch_bounds__(256) void k_pack(const int* __restrict__ A,
                                              const float* __restrict__ u1,
                                              unsigned int* __restrict__ Wb32,
                                              float* __restrict__ den1) {
    __shared__ unsigned short msh[8][512];
    const int tid = threadIdx.x, wv = tid >> 6, lane = tid & 63;
    const int row0 = blockIdx.x * 8;
    float dsum0 = 0.f, dsum1 = 0.f;
    const int r0 = row0 + wv * 2, r1 = r0 + 1;
    for (int c = 0; c < 8; ++c) {
        const int j = c * 1024 + lane * 16;
        const int4* A0 = (const int4*)(A + (size_t)r0 * NN + j);
        const int4* A1 = (const int4*)(A + (size_t)r1 * NN + j);
        const float4* U4 = (const float4*)(u1 + j);
        int4 a0 = A0[0], a1 = A0[1], a2 = A0[2], a3 = A0[3];
        int4 b0 = A1[0], b1 = A1[1], b2 = A1[2], b3 = A1[3];
        float4 u0 = U4[0], u4 = U4[1], u8 = U4[2], uc = U4[3];
        unsigned int m0 = 0, m1 = 0;
#define DO4(AV, BV, UV, SH)                                            \
        m0 |= ((AV.x != 0) << (SH)) | ((AV.y != 0) << (SH + 1)) |      \
              ((AV.z != 0) << (SH + 2)) | ((AV.w != 0) << (SH + 3));   \
        m1 |= ((BV.x != 0) << (SH)) | ((BV.y != 0) << (SH + 1)) |      \
              ((BV.z != 0) << (SH + 2)) | ((BV.w != 0) << (SH + 3));   \
        dsum0 += (AV.x != 0 ? UV.x : 0.f) + (AV.y != 0 ? UV.y : 0.f) + \
                 (AV.z != 0 ? UV.z : 0.f) + (AV.w != 0 ? UV.w : 0.f);  \
        dsum1 += (BV.x != 0 ? UV.x : 0.f) + (BV.y != 0 ? UV.y : 0.f) + \
                 (BV.z != 0 ? UV.z : 0.f) + (BV.w != 0 ? UV.w : 0.f);
        DO4(a0, b0, u0, 0) DO4(a1, b1, u4, 4) DO4(a2, b2, u8, 8) DO4(a3, b3, uc, 12)
#undef DO4
        msh[wv * 2 + 0][c * 64 + lane] = (unsigned short)m0;
        msh[wv * 2 + 1][c * 64 + lane] = (unsigned short)m1;
    }
#pragma unroll
    for (int off = 32; off; off >>= 1) {
        dsum0 += __shfl_down(dsum0, off);
        dsum1 += __shfl_down(dsum1, off);
    }
    if (lane == 0) { den1[r0] = dsum0; den1[r1] = dsum1; }
    __syncthreads();
    {
        const int r = tid >> 5, i = tid & 31;
        const uint4* src = (const uint4*)&msh[r][0];
        uint4* dst = (uint4*)(Wb32 + (size_t)(row0 + r) * 256);
        dst[i] = src[i];
        dst[i + 32] = src[i + 32];
    }
}

// ---------------------------------------------------------------------------
// K3: layer-1 MFMA. grid (128 node-groups, 16 ksplits). WAVE = M-TILE:
// each Gt fragment loaded once per block; B built per n-tile from bits (VALU).
// ---------------------------------------------------------------------------
__global__ __launch_bounds__(256) void k_attn1(const unsigned int* __restrict__ Wb32,
                                               const unsigned int* __restrict__ Gt1h,
                                               const unsigned int* __restrict__ Gt1l,
                                               float* __restrict__ num1p) {
    __shared__ unsigned int bw[64 * 20];    // 64 rows x 16 u32, stride 20
    const int tid = threadIdx.x, wv = tid >> 6, lane = tid & 63;
    const int node0 = blockIdx.x * 64;
    const int kt0 = blockIdx.y * 16;
    {
        const int r = tid >> 2, part = tid & 3;
        const uint4* src = (const uint4*)(Wb32 + (size_t)(node0 + r) * 256 + kt0 + part * 4);
        *(uint4*)&bw[r * 20 + part * 4] = src[0];
    }
    __syncthreads();
    const int n = lane & 15, quad = lane >> 4;
    const int mt = wv;
    f32x4 acc[4];
#pragma unroll
    for (int nt = 0; nt < 4; ++nt) acc[nt] = (f32x4){0.f, 0.f, 0.f, 0.f};
#pragma unroll 4
    for (int ks = 0; ks < 16; ++ks) {
        size_t base = ((size_t)(mt * 256 + kt0 + ks) * 64 + lane) * 4;
        V16 ah, al;
        ah.u = *(const uint4*)(Gt1h + base);
        al.u = *(const uint4*)(Gt1l + base);
#pragma unroll
        for (int nt = 0; nt < 4; ++nt) {
            unsigned int by8 = (bw[(nt * 16 + n) * 20 + ks] >> (quad * 8)) & 0xFFu;
            V16 bf;
            bf.u = make_uint4(bits2bf(by8), bits2bf(by8 >> 2),
                              bits2bf(by8 >> 4), bits2bf(by8 >> 6));
            acc[nt] = __builtin_amdgcn_mfma_f32_16x16x32_bf16(ah.s, bf.s, acc[nt], 0, 0, 0);
            acc[nt] = __builtin_amdgcn_mfma_f32_16x16x32_bf16(al.s, bf.s, acc[nt], 0, 0, 0);
        }
    }
    const int s = blockIdx.y;
#pragma unroll
    for (int nt = 0; nt < 4; ++nt) {
        const int node = node0 + nt * 16 + n;
        *(f32x4*)&num1p[((size_t)s * NN + node) * 64 + mt * 16 + quad * 4] = acc[nt];
    }
}

// ---------------------------------------------------------------------------
// K4: layer-1 epilogue + layer-2 prep. Writes Gt2 tiled, M=48
// (mt 0,1 = features, mt 2 = [u2; zeros] so den2 rides the layer-2 MFMA).
// ---------------------------------------------------------------------------
__global__ __launch_bounds__(512) void k_ep1(const float* __restrict__ num1p,
                                             const float* __restrict__ den1,
                                             const float* __restrict__ W21,
                                             const float* __restrict__ b21,
                                             const float* __restrict__ Wg2,
                                             const float* __restrict__ a2,
                                             unsigned int* __restrict__ Gt2h,
                                             unsigned int* __restrict__ Gt2l) {
    __shared__ float w21sh[64 * 64];
    __shared__ float wg2sh[64 * 32];
    __shared__ float zsh[8][64];
    __shared__ float osh[8][64];
    __shared__ unsigned int g2sh[32][33];
    __shared__ unsigned int u2sh[32];
    const int tid = threadIdx.x, wv = tid >> 6, lane = tid & 63;
    const int node0 = blockIdx.x * 32;
    {
        const float4* s4 = (const float4*)W21;
        float4* d4 = (float4*)w21sh;
        d4[tid] = s4[tid];
        d4[tid + 512] = s4[tid + 512];
        ((float4*)wg2sh)[tid] = ((const float4*)Wg2)[tid];
    }
    const float bb = b21[lane];
    const int l32 = lane & 31;
    const float a2v = (lane < 32) ? a2[32 + l32] : 0.f;
    __syncthreads();
    for (int it = 0; it < 4; ++it) {
        const int node = node0 + wv * 4 + it;
        float sacc = 0.f;
#pragma unroll
        for (int sp = 0; sp < 16; ++sp)
            sacc += num1p[((size_t)sp * NN + node) * 64 + lane];
        zsh[wv][lane] = sacc / den1[node];
        __builtin_amdgcn_wave_barrier();
        float o0 = 0.f, o1 = 0.f, o2 = 0.f, o3 = 0.f;
        for (int c = 0; c < 64; c += 4) {
            o0 += zsh[wv][c + 0] * w21sh[(c + 0) * 64 + lane];
            o1 += zsh[wv][c + 1] * w21sh[(c + 1) * 64 + lane];
            o2 += zsh[wv][c + 2] * w21sh[(c + 2) * 64 + lane];
            o3 += zsh[wv][c + 3] * w21sh[(c + 3) * 64 + lane];
        }
        float o = elu_f(bb + ((o0 + o1) + (o2 + o3)));
        osh[wv][lane] = o;
        __builtin_amdgcn_wave_barrier();
        float h0 = 0.f, h1 = 0.f;
        for (int c = 0; c < 64; c += 2) {
            h0 += osh[wv][c + 0] * wg2sh[(c + 0) * 32 + l32];
            h1 += osh[wv][c + 1] * wg2sh[(c + 1) * 32 + l32];
        }
        float hval = h0 + h1;
        float pp = hval * a2v;
#pragma unroll
        for (int off = 32; off; off >>= 1) pp += __shfl_down(pp, off);
        float d2 = __shfl(pp, 0);
        float uu = expf(d2);
        const int nodeloc = wv * 4 + it;
        if (lane == 0) u2sh[nodeloc] = split_pack(uu);
        if (lane < 32) g2sh[l32][nodeloc] = split_pack(uu * hval);
    }
    __syncthreads();
    if (tid < 192) {   // tiled Gt2 writer: 3 mt x 64 lanes
        const int mt = tid >> 6, lane2 = tid & 63;
        const int ml = lane2 & 15, quad = lane2 >> 4;
        uint4 hv, lv;
        unsigned int g0, g1;
#define PACK_Q(Q, F)                                                   \
        {                                                              \
            int j0 = quad * 8 + 2 * Q;                                 \
            if (mt < 2) { g0 = g2sh[mt * 16 + ml][j0];                 \
                          g1 = g2sh[mt * 16 + ml][j0 + 1]; }           \
            else if (ml == 0) { g0 = u2sh[j0]; g1 = u2sh[j0 + 1]; }    \
            else { g0 = 0; g1 = 0; }                                   \
            hv.F = (g0 >> 16) | (g1 & 0xFFFF0000u);                    \
            lv.F = (g0 & 0xFFFFu) | (g1 << 16);                        \
        }
        PACK_Q(0, x) PACK_Q(1, y) PACK_Q(2, z) PACK_Q(3, w)
#undef PACK_Q
        size_t base = ((size_t)(mt * 256 + blockIdx.x) * 64 + lane2) * 4;
        *(uint4*)(Gt2h + base) = hv;
        *(uint4*)(Gt2l + base) = lv;
    }
}

// ---------------------------------------------------------------------------
// K5: layer-2 MFMA, M=48. Wave = m-tile (waves 0-2; wave 3 idles after
// staging). grid (128,16).
// ---------------------------------------------------------------------------
__global__ __launch_bounds__(256) void k_attn2(const unsigned int* __restrict__ Wb32,
                                               const unsigned int* __restrict__ Gt2h,
                                               const unsigned int* __restrict__ Gt2l,
                                               float* __restrict__ num2p) {
    __shared__ unsigned int bw[64 * 20];
    const int tid = threadIdx.x, wv = tid >> 6, lane = tid & 63;
    const int node0 = blockIdx.x * 64;
    const int kt0 = blockIdx.y * 16;
    {
        const int r = tid >> 2, part = tid & 3;
        const uint4* src = (const uint4*)(Wb32 + (size_t)(node0 + r) * 256 + kt0 + part * 4);
        *(uint4*)&bw[r * 20 + part * 4] = src[0];
    }
    __syncthreads();
    if (wv == 3) return;
    const int n = lane & 15, quad = lane >> 4;
    const int mt = wv;
    f32x4 acc[4];
#pragma unroll
    for (int nt = 0; nt < 4; ++nt) acc[nt] = (f32x4){0.f, 0.f, 0.f, 0.f};
#pragma unroll 4
    for (int ks = 0; ks < 16; ++ks) {
        size_t base = ((size_t)(mt * 256 + kt0 + ks) * 64 + lane) * 4;
        V16 ah, al;
        ah.u = *(const uint4*)(Gt2h + base);
        al.u = *(const uint4*)(Gt2l + base);
#pragma unroll
        for (int nt = 0; nt < 4; ++nt) {
            unsigned int by8 = (bw[(nt * 16 + n) * 20 + ks] >> (quad * 8)) & 0xFFu;
            V16 bf;
            bf.u = make_uint4(bits2bf(by8), bits2bf(by8 >> 2),
                              bits2bf(by8 >> 4), bits2bf(by8 >> 6));
            acc[nt] = __builtin_amdgcn_mfma_f32_16x16x32_bf16(ah.s, bf.s, acc[nt], 0, 0, 0);
            acc[nt] = __builtin_amdgcn_mfma_f32_16x16x32_bf16(al.s, bf.s, acc[nt], 0, 0, 0);
        }
    }
    const int s = blockIdx.y;
#pragma unroll
    for (int nt = 0; nt < 4; ++nt) {
        const int node = node0 + nt * 16 + n;
        *(f32x4*)&num2p[((size_t)s * NN + node) * 48 + mt * 16 + quad * 4] = acc[nt];
    }
}

// ---------------------------------------------------------------------------
// K6: layer-2 epilogue + column partials for mean.
// ---------------------------------------------------------------------------
__global__ __launch_bounds__(512) void k_ep2(const float* __restrict__ num2p,
                                             const float* __restrict__ W22,
                                             const float* __restrict__ b22,
                                             float* __restrict__ gpart) {
    __shared__ float w22sh[32 * 64];
    __shared__ float zsh[8][32];
    __shared__ float gsh[8][64];
    const int tid = threadIdx.x, wv = tid >> 6, lane = tid & 63;
    ((float4*)w22sh)[tid] = ((const float4*)W22)[tid];
    const float bb = b22[lane];
    __syncthreads();
    const int row = blockIdx.x * 8 + wv;
    float val = 0.f;
    if (lane < 33) {
#pragma unroll
        for (int sp = 0; sp < 16; ++sp)
            val += num2p[((size_t)sp * NN + row) * 48 + lane];
    }
    float den = __shfl(val, 32);
    if (lane < 32) zsh[wv][lane] = val / den;
    __builtin_amdgcn_wave_barrier();
    float o0 = 0.f, o1 = 0.f;
    for (int c = 0; c < 32; c += 2) {
        o0 += zsh[wv][c + 0] * w22sh[(c + 0) * 64 + lane];
        o1 += zsh[wv][c + 1] * w22sh[(c + 1) * 64 + lane];
    }
    gsh[wv][lane] = elu_f(bb + o0 + o1);
    __syncthreads();
    if (tid < 64) {
        float s = 0.f;
#pragma unroll
        for (int w = 0; w < 8; ++w) s += gsh[w][tid];
        gpart[(size_t)blockIdx.x * 64 + tid] = s;
    }
}

// ---------------------------------------------------------------------------
// K7: mean + MLP head.
// ---------------------------------------------------------------------------
__global__ __launch_bounds__(256) void k_head(const float* __restrict__ gpart,
                                              const float* __restrict__ M1,
                                              const float* __restrict__ bm1,
                                              const float* __restrict__ M2,
                                              const float* __restrict__ bm2,
                                              float* __restrict__ outp) {
    __shared__ float part[4][64];
    __shared__ float gsh[64];
    __shared__ float hsh[64];
    const int tid = threadIdx.x, col = tid & 63, p = tid >> 6;
    float s = 0.f;
    for (int b = p * 256; b < p * 256 + 256; ++b)
        s += gpart[(size_t)b * 64 + col];
    part[p][col] = s;
    __syncthreads();
    if (tid < 64)
        gsh[tid] = (part[0][tid] + part[1][tid] + part[2][tid] + part[3][tid])
                   * (1.0f / 8192.0f);
    __syncthreads();
    if (tid < 64) {
        float h = bm1[tid];
        for (int c = 0; c < 64; ++c) h += gsh[c] * M1[c * 64 + tid];
        hsh[tid] = h > 0.f ? h : 0.f;
    }
    __syncthreads();
    if (tid < 2) {
        float o = bm2[tid];
        for (int j = 0; j < 64; ++j) o += hsh[j] * M2[j * 2 + tid];
        outp[tid] = o;
    }
}

// ---------------------------------------------------------------------------
extern "C" void kernel_launch(void* const* d_in, const int* in_sizes, int n_in,
                              void* d_out, int out_size, void* d_ws, size_t ws_size,
                              hipStream_t stream) {
    const float* X   = (const float*)d_in[0];
    const int*   A   = (const int*)  d_in[1];
    const float* W1  = (const float*)d_in[2];
    const float* a1  = (const float*)d_in[3];
    const float* W21 = (const float*)d_in[4];
    const float* b21 = (const float*)d_in[5];
    const float* Wg2 = (const float*)d_in[6];
    const float* a2  = (const float*)d_in[7];
    const float* W22 = (const float*)d_in[8];
    const float* b22 = (const float*)d_in[9];
    const float* M1  = (const float*)d_in[10];
    const float* bm1 = (const float*)d_in[11];
    const float* M2  = (const float*)d_in[12];
    const float* bm2 = (const float*)d_in[13];
    float* out = (float*)d_out;

    char* ws = (char*)d_ws;
    unsigned int* Wbits = (unsigned int*)(ws + OFF_WBITS);
    unsigned int* Gt1h  = (unsigned int*)(ws + OFF_GT1H);
    unsigned int* Gt1l  = (unsigned int*)(ws + OFF_GT1L);
    unsigned int* Gt2h  = (unsigned int*)(ws + OFF_GT2H);
    unsigned int* Gt2l  = (unsigned int*)(ws + OFF_GT2L);
    unsigned int* WtAh  = (unsigned int*)(ws + OFF_WTAH);
    unsigned int* WtAl  = (unsigned int*)(ws + OFF_WTAL);
    float* Dp    = (float*)(ws + OFF_DP);
    float* u1    = (float*)(ws + OFF_U1);
    float* den1  = (float*)(ws + OFF_DEN1);
    float* gpart = (float*)(ws + OFF_GPART);
    float* nump  = (float*)(ws + OFF_NUMP);

    k_wsetup<<<24, 256, 0, stream>>>(W1, WtAh, WtAl);
    k_xw1m <<<dim3(128, 4), 256, 0, stream>>>(X, WtAh, WtAl, Dp);
    k_xcomb<<<256, 256, 0, stream>>>(Dp, a1, Gt1h, Gt1l, u1);
    k_pack <<<1024, 256, 0, stream>>>(A, u1, Wbits, den1);
    k_attn1<<<dim3(128, 16), 256, 0, stream>>>(Wbits, Gt1h, Gt1l, nump);
    k_ep1  <<<256, 512, 0, stream>>>(nump, den1, W21, b21, Wg2, a2, Gt2h, Gt2l);
    k_attn2<<<dim3(128, 16), 256, 0, stream>>>(Wbits, Gt2h, Gt2l, nump);
    k_ep2  <<<1024, 512, 0, stream>>>(nump, W22, b22, gpart);
    k_head <<<1, 256, 0, stream>>>(gpart, M1, bm1, M2, bm2, out);
}